// Round 3
// baseline (1286.388 us; speedup 1.0000x reference)
//
#include <hip/hip_runtime.h>
#include <math.h>

#define N_NODES 100000
#define N_EDGES 1600000
#define HD 64

__global__ void k_zero_i32(int* __restrict__ p, int n){
  int i = blockIdx.x*blockDim.x + threadIdx.x;
  if(i<n) p[i]=0;
}

__global__ void k_count_deg(const int* __restrict__ dst, int* __restrict__ deg, int n){
  int i = blockIdx.x*blockDim.x + threadIdx.x;
  if(i<n) atomicAdd(&deg[dst[i]], 1);
}

// per-256-chunk sums of deg -> partial[block]
__global__ void k_block_sums(const int* __restrict__ deg, int* __restrict__ partial, int n){
  __shared__ int s[256];
  int t=threadIdx.x, i=blockIdx.x*256+t;
  s[t] = (i<n)? deg[i] : 0;
  __syncthreads();
  for(int off=128; off>0; off>>=1){ if(t<off) s[t]+=s[t+off]; __syncthreads(); }
  if(t==0) partial[blockIdx.x]=s[0];
}

// exclusive scan of partial[0..nblk) in one 512-thread block (nblk<=512)
__global__ void k_scan_partials(int* __restrict__ partial, int nblk){
  __shared__ int s[512];
  int t=threadIdx.x;
  int v = (t<nblk)? partial[t] : 0;
  s[t]=v;
  __syncthreads();
  for(int off=1; off<512; off<<=1){
    int add = (t>=off)? s[t-off]:0;
    __syncthreads();
    s[t]+=add;
    __syncthreads();
  }
  if(t<nblk) partial[t] = s[t]-v;  // exclusive
}

// rowptr[i] = exclusive scan of deg; invdeg[i] = 1/max(deg,1); rowptr[N]=E
__global__ void k_rowptr_invdeg(const int* __restrict__ deg, const int* __restrict__ partial,
                                int* __restrict__ rowptr, float* __restrict__ invdeg, int n, int ne){
  __shared__ int s[256];
  int t=threadIdx.x, i=blockIdx.x*256+t;
  int v = (i<n)? deg[i]:0;
  s[t]=v;
  __syncthreads();
  for(int off=1; off<256; off<<=1){
    int add=(t>=off)? s[t-off]:0;
    __syncthreads();
    s[t]+=add;
    __syncthreads();
  }
  if(i<n){
    rowptr[i] = partial[blockIdx.x] + s[t]-v;
    invdeg[i] = 1.0f/fmaxf((float)v,1.0f);
  }
  if(i==0) rowptr[n]=ne;
}

__global__ void k_scatter(const int* __restrict__ src, const int* __restrict__ dst,
                          const int* __restrict__ rowptr, int* __restrict__ cursor,
                          int* __restrict__ csr, int n){
  int i = blockIdx.x*blockDim.x + threadIdx.x;
  if(i<n){
    int d = dst[i];
    int p = atomicAdd(&cursor[d],1);
    csr[rowptr[d]+p] = src[i];
  }
}

// One wave (64 lanes) per node. lane = feature index.
// h_out = relu( mean_agg(h_in) @ Wl + b + h_in @ Wr )
// Fused JK projection: partial[node] (+)= dot(h_out, wseg); last layer -> sigmoid -> finout.
__global__ __launch_bounds__(256) void k_sage(
    const float* __restrict__ hin, float* __restrict__ hout,
    const int* __restrict__ rowptr, const int* __restrict__ csr,
    const float* __restrict__ invdeg,
    const float* __restrict__ Wl, const float* __restrict__ bvec, const float* __restrict__ Wr,
    const float* __restrict__ wseg, const float* __restrict__ blin,
    float* __restrict__ partial, float* __restrict__ finout,
    int first, int nnodes)
{
  __shared__ float wl[64*64];
  __shared__ float wr[64*64];
  __shared__ float bs[64];
  __shared__ float wsg[64];
  int t=threadIdx.x;
  {
    const float4* a=(const float4*)Wl; const float4* b=(const float4*)Wr;
    float4* sa=(float4*)wl; float4* sb=(float4*)wr;
    #pragma unroll
    for(int r=0;r<4;r++){ sa[t+r*256]=a[t+r*256]; sb[t+r*256]=b[t+r*256]; }
    if(t<64){ bs[t]=bvec[t]; wsg[t]=wseg[t]; }
  }
  __syncthreads();
  int lane=t&63, wid=t>>6;
  int node=blockIdx.x*4+wid;
  if(node>=nnodes) return;
  int start=rowptr[node], end=rowptr[node+1];
  float agg=0.f;
  for(int e=start;e<end;++e){
    int s=csr[e];
    agg += hin[(size_t)s*HD+lane];
  }
  agg *= invdeg[node];
  float hn = hin[(size_t)node*HD+lane];
  float acc = bs[lane];
  #pragma unroll
  for(int k=0;k<64;k++){
    acc = fmaf(__shfl(agg,k,64), wl[k*64+lane], acc);
    acc = fmaf(__shfl(hn,k,64),  wr[k*64+lane], acc);
  }
  float r = fmaxf(acc, 0.f);
  hout[(size_t)node*HD+lane] = r;
  float c = r*wsg[lane];
  #pragma unroll
  for(int off=32; off>0; off>>=1) c += __shfl_xor(c, off, 64);
  if(lane==0){
    float p = first ? (blin[0]+c) : (partial[node]+c);
    if(finout) finout[node] = 1.0f/(1.0f+expf(-p));
    else partial[node]=p;
  }
}

extern "C" void kernel_launch(void* const* d_in, const int* in_sizes, int n_in,
                              void* d_out, int out_size, void* d_ws, size_t ws_size,
                              hipStream_t stream){
  const float* x    =(const float*)d_in[0];
  const int*   ei   =(const int*)  d_in[1];
  const float* W1l  =(const float*)d_in[2];
  const float* b1   =(const float*)d_in[3];
  const float* W1r  =(const float*)d_in[4];
  const float* W2l  =(const float*)d_in[5];
  const float* b2   =(const float*)d_in[6];
  const float* W2r  =(const float*)d_in[7];
  const float* W3l  =(const float*)d_in[8];
  const float* b3   =(const float*)d_in[9];
  const float* W3r  =(const float*)d_in[10];
  const float* Wlin =(const float*)d_in[11];
  const float* blin =(const float*)d_in[12];
  float* out=(float*)d_out;

  const int N=N_NODES, E=N_EDGES;
  char* ws=(char*)d_ws;
  size_t off=0;
  auto take=[&](size_t bytes)->char*{ char* p=ws+off; off=(off+bytes+255)&~(size_t)255; return p; };
  int*   deg      =(int*)  take((size_t)N*4);
  int*   rowptr   =(int*)  take((size_t)(N+1)*4);
  int*   cursor   =(int*)  take((size_t)N*4);
  int*   csr      =(int*)  take((size_t)E*4);
  int*   partialS =(int*)  take(512*4);
  float* invdeg   =(float*)take((size_t)N*4);
  float* hA       =(float*)take((size_t)N*HD*4);
  float* hB       =(float*)take((size_t)N*HD*4);
  float* pacc     =(float*)take((size_t)N*4);

  const int NB=(N+255)/256;           // 391
  const int EB=(E+255)/256;           // 6250

  k_zero_i32     <<<NB, 256, 0, stream>>>(deg, N);
  k_count_deg    <<<EB, 256, 0, stream>>>(ei+E, deg, E);
  k_block_sums   <<<NB, 256, 0, stream>>>(deg, partialS, N);
  k_scan_partials<<<1, 512, 0, stream>>>(partialS, NB);
  k_rowptr_invdeg<<<NB, 256, 0, stream>>>(deg, partialS, rowptr, invdeg, N, E);
  k_zero_i32     <<<NB, 256, 0, stream>>>(cursor, N);
  k_scatter      <<<EB, 256, 0, stream>>>(ei, ei+E, rowptr, cursor, csr, E);

  dim3 sg((N+3)/4);
  k_sage<<<sg, 256, 0, stream>>>(x,  hA, rowptr, csr, invdeg, W1l,b1,W1r, Wlin+0,   blin, pacc, (float*)nullptr, 1, N);
  k_sage<<<sg, 256, 0, stream>>>(hA, hB, rowptr, csr, invdeg, W2l,b2,W2r, Wlin+64,  blin, pacc, (float*)nullptr, 0, N);
  k_sage<<<sg, 256, 0, stream>>>(hB, hA, rowptr, csr, invdeg, W3l,b3,W3r, Wlin+128, blin, pacc, out, 0, N);
}

// Round 4
// 824.738 us; speedup vs baseline: 1.5598x; 1.5598x over previous
//
#include <hip/hip_runtime.h>
#include <math.h>

#define N_NODES 100000
#define N_EDGES 1600000
#define HD 64

__global__ void k_zero_i32(int* __restrict__ p, int n){
  int i = blockIdx.x*blockDim.x + threadIdx.x;
  if(i<n) p[i]=0;
}

__global__ void k_count_deg(const int* __restrict__ dst, int* __restrict__ deg, int n){
  int i = blockIdx.x*blockDim.x + threadIdx.x;
  if(i<n) atomicAdd(&deg[dst[i]], 1);
}

// per-256-chunk sums of deg -> partial[block]
__global__ void k_block_sums(const int* __restrict__ deg, int* __restrict__ partial, int n){
  __shared__ int s[256];
  int t=threadIdx.x, i=blockIdx.x*256+t;
  s[t] = (i<n)? deg[i] : 0;
  __syncthreads();
  for(int off=128; off>0; off>>=1){ if(t<off) s[t]+=s[t+off]; __syncthreads(); }
  if(t==0) partial[blockIdx.x]=s[0];
}

// exclusive scan of partial[0..nblk) in one 512-thread block (nblk<=512)
__global__ void k_scan_partials(int* __restrict__ partial, int nblk){
  __shared__ int s[512];
  int t=threadIdx.x;
  int v = (t<nblk)? partial[t] : 0;
  s[t]=v;
  __syncthreads();
  for(int off=1; off<512; off<<=1){
    int add = (t>=off)? s[t-off]:0;
    __syncthreads();
    s[t]+=add;
    __syncthreads();
  }
  if(t<nblk) partial[t] = s[t]-v;  // exclusive
}

// rowptr[i]=exclusive scan of deg; invdeg=1/max(deg,1); cursor=0; rowptr[N]=E
__global__ void k_rowptr_invdeg(const int* __restrict__ deg, const int* __restrict__ partial,
                                int* __restrict__ rowptr, float* __restrict__ invdeg,
                                int* __restrict__ cursor, int n, int ne){
  __shared__ int s[256];
  int t=threadIdx.x, i=blockIdx.x*256+t;
  int v = (i<n)? deg[i]:0;
  s[t]=v;
  __syncthreads();
  for(int off=1; off<256; off<<=1){
    int add=(t>=off)? s[t-off]:0;
    __syncthreads();
    s[t]+=add;
    __syncthreads();
  }
  if(i<n){
    rowptr[i] = partial[blockIdx.x] + s[t]-v;
    invdeg[i] = 1.0f/fmaxf((float)v,1.0f);
    cursor[i] = 0;
  }
  if(i==0) rowptr[n]=ne;
}

__global__ void k_scatter(const int* __restrict__ src, const int* __restrict__ dst,
                          const int* __restrict__ rowptr, int* __restrict__ cursor,
                          int* __restrict__ csr, int n){
  int i = blockIdx.x*blockDim.x + threadIdx.x;
  if(i<n){
    int d = dst[i];
    int p = atomicAdd(&cursor[d],1);
    csr[rowptr[d]+p] = src[i];
  }
}

// One wave (64 lanes) per node, 8 nodes per 512-thread block. lane = feature.
// h_out = relu( mean_agg(h_in) @ Wl + b + h_in @ Wr )
// Fused JK projection: partial[node] (+)= dot(h_out, wseg); last layer -> sigmoid.
__global__ __launch_bounds__(512) void k_sage(
    const float* __restrict__ hin, float* __restrict__ hout,
    const int* __restrict__ rowptr, const int* __restrict__ csr,
    const float* __restrict__ invdeg,
    const float* __restrict__ Wl, const float* __restrict__ bvec, const float* __restrict__ Wr,
    const float* __restrict__ wseg, const float* __restrict__ blin,
    float* __restrict__ partial, float* __restrict__ finout,
    int first, int nnodes)
{
  __shared__ float wl[64*64];
  __shared__ float wr[64*64];
  __shared__ float bs[64];
  __shared__ float wsg[64];
  int t=threadIdx.x;
  {
    const float4* a=(const float4*)Wl; const float4* b=(const float4*)Wr;
    float4* sa=(float4*)wl; float4* sb=(float4*)wr;
    #pragma unroll
    for(int r=0;r<2;r++){ sa[t+r*512]=a[t+r*512]; sb[t+r*512]=b[t+r*512]; }
    if(t<64){ bs[t]=bvec[t]; wsg[t]=wseg[t]; }
  }
  __syncthreads();
  int lane=t&63, wid=t>>6;
  int node=blockIdx.x*8+wid;
  if(node>=nnodes) return;
  int start=rowptr[node], end=rowptr[node+1];

  // unroll-by-8 gather: batch index loads, then 8 independent row gathers (MLP)
  float a0=0.f,a1=0.f,a2=0.f,a3=0.f;
  int e=start;
  for(; e+8<=end; e+=8){
    int s0=csr[e+0], s1=csr[e+1], s2=csr[e+2], s3=csr[e+3];
    int s4=csr[e+4], s5=csr[e+5], s6=csr[e+6], s7=csr[e+7];
    float v0=hin[(size_t)s0*HD+lane], v1=hin[(size_t)s1*HD+lane];
    float v2=hin[(size_t)s2*HD+lane], v3=hin[(size_t)s3*HD+lane];
    float v4=hin[(size_t)s4*HD+lane], v5=hin[(size_t)s5*HD+lane];
    float v6=hin[(size_t)s6*HD+lane], v7=hin[(size_t)s7*HD+lane];
    a0+=v0; a1+=v1; a2+=v2; a3+=v3;
    a0+=v4; a1+=v5; a2+=v6; a3+=v7;
  }
  for(; e<end; ++e) a0 += hin[(size_t)csr[e]*HD+lane];
  float agg = (a0+a1)+(a2+a3);
  agg *= invdeg[node];

  float hn = hin[(size_t)node*HD+lane];
  float acc = bs[lane];
  #pragma unroll
  for(int k=0;k<64;k++){
    acc = fmaf(__shfl(agg,k,64), wl[k*64+lane], acc);
    acc = fmaf(__shfl(hn,k,64),  wr[k*64+lane], acc);
  }
  float r = fmaxf(acc, 0.f);
  hout[(size_t)node*HD+lane] = r;
  float c = r*wsg[lane];
  #pragma unroll
  for(int off=32; off>0; off>>=1) c += __shfl_xor(c, off, 64);
  if(lane==0){
    float p = first ? (blin[0]+c) : (partial[node]+c);
    if(finout) finout[node] = 1.0f/(1.0f+expf(-p));
    else partial[node]=p;
  }
}

extern "C" void kernel_launch(void* const* d_in, const int* in_sizes, int n_in,
                              void* d_out, int out_size, void* d_ws, size_t ws_size,
                              hipStream_t stream){
  const float* x    =(const float*)d_in[0];
  const int*   ei   =(const int*)  d_in[1];
  const float* W1l  =(const float*)d_in[2];
  const float* b1   =(const float*)d_in[3];
  const float* W1r  =(const float*)d_in[4];
  const float* W2l  =(const float*)d_in[5];
  const float* b2   =(const float*)d_in[6];
  const float* W2r  =(const float*)d_in[7];
  const float* W3l  =(const float*)d_in[8];
  const float* b3   =(const float*)d_in[9];
  const float* W3r  =(const float*)d_in[10];
  const float* Wlin =(const float*)d_in[11];
  const float* blin =(const float*)d_in[12];
  float* out=(float*)d_out;

  const int N=N_NODES, E=N_EDGES;
  char* ws=(char*)d_ws;
  size_t off=0;
  auto take=[&](size_t bytes)->char*{ char* p=ws+off; off=(off+bytes+255)&~(size_t)255; return p; };
  int*   deg      =(int*)  take((size_t)N*4);
  int*   rowptr   =(int*)  take((size_t)(N+1)*4);
  int*   cursor   =(int*)  take((size_t)N*4);
  int*   csr      =(int*)  take((size_t)E*4);
  int*   partialS =(int*)  take(512*4);
  float* invdeg   =(float*)take((size_t)N*4);
  float* hA       =(float*)take((size_t)N*HD*4);
  float* hB       =(float*)take((size_t)N*HD*4);
  float* pacc     =(float*)take((size_t)N*4);

  const int NB=(N+255)/256;           // 391
  const int EB=(E+255)/256;           // 6250

  k_zero_i32     <<<NB, 256, 0, stream>>>(deg, N);
  k_count_deg    <<<EB, 256, 0, stream>>>(ei+E, deg, E);
  k_block_sums   <<<NB, 256, 0, stream>>>(deg, partialS, N);
  k_scan_partials<<<1, 512, 0, stream>>>(partialS, NB);
  k_rowptr_invdeg<<<NB, 256, 0, stream>>>(deg, partialS, rowptr, invdeg, cursor, N, E);
  k_scatter      <<<EB, 256, 0, stream>>>(ei, ei+E, rowptr, cursor, csr, E);

  dim3 sg((N+7)/8);
  k_sage<<<sg, 512, 0, stream>>>(x,  hA, rowptr, csr, invdeg, W1l,b1,W1r, Wlin+0,   blin, pacc, (float*)nullptr, 1, N);
  k_sage<<<sg, 512, 0, stream>>>(hA, hB, rowptr, csr, invdeg, W2l,b2,W2r, Wlin+64,  blin, pacc, (float*)nullptr, 0, N);
  k_sage<<<sg, 512, 0, stream>>>(hB, hA, rowptr, csr, invdeg, W3l,b3,W3r, Wlin+128, blin, pacc, out, 0, N);
}

// Round 8
// 762.047 us; speedup vs baseline: 1.6881x; 1.0823x over previous
//
#include <hip/hip_runtime.h>
#include <math.h>

#define N_NODES 100000
#define N_EDGES 1600000
#define HD 64

__global__ void k_zero_i32(int* __restrict__ p, int n){
  int i = blockIdx.x*blockDim.x + threadIdx.x;
  if(i<n) p[i]=0;
}

__global__ void k_count_deg(const int* __restrict__ dst, int* __restrict__ deg, int n){
  int i = blockIdx.x*blockDim.x + threadIdx.x;
  if(i<n) atomicAdd(&deg[dst[i]], 1);
}

// per-256-chunk sums of deg -> partial[block]
__global__ void k_block_sums(const int* __restrict__ deg, int* __restrict__ partial, int n){
  __shared__ int s[256];
  int t=threadIdx.x, i=blockIdx.x*256+t;
  s[t] = (i<n)? deg[i] : 0;
  __syncthreads();
  for(int off=128; off>0; off>>=1){ if(t<off) s[t]+=s[t+off]; __syncthreads(); }
  if(t==0) partial[blockIdx.x]=s[0];
}

// exclusive scan of partial[0..nblk) in one 512-thread block (nblk<=512)
__global__ void k_scan_partials(int* __restrict__ partial, int nblk){
  __shared__ int s[512];
  int t=threadIdx.x;
  int v = (t<nblk)? partial[t] : 0;
  s[t]=v;
  __syncthreads();
  for(int off=1; off<512; off<<=1){
    int add = (t>=off)? s[t-off]:0;
    __syncthreads();
    s[t]+=add;
    __syncthreads();
  }
  if(t<nblk) partial[t] = s[t]-v;  // exclusive
}

// rowptr[i]=exclusive scan of deg; invdeg=1/max(deg,1); cursor=0; rowptr[N]=E
__global__ void k_rowptr_invdeg(const int* __restrict__ deg, const int* __restrict__ partial,
                                int* __restrict__ rowptr, float* __restrict__ invdeg,
                                int* __restrict__ cursor, int n, int ne){
  __shared__ int s[256];
  int t=threadIdx.x, i=blockIdx.x*256+t;
  int v = (i<n)? deg[i]:0;
  s[t]=v;
  __syncthreads();
  for(int off=1; off<256; off<<=1){
    int add=(t>=off)? s[t-off]:0;
    __syncthreads();
    s[t]+=add;
    __syncthreads();
  }
  if(i<n){
    rowptr[i] = partial[blockIdx.x] + s[t]-v;
    invdeg[i] = 1.0f/fmaxf((float)v,1.0f);
    cursor[i] = 0;
  }
  if(i==0) rowptr[n]=ne;
}

__global__ void k_scatter(const int* __restrict__ src, const int* __restrict__ dst,
                          const int* __restrict__ rowptr, int* __restrict__ cursor,
                          int* __restrict__ csr, int n){
  int i = blockIdx.x*blockDim.x + threadIdx.x;
  if(i<n){
    int d = dst[i];
    int p = atomicAdd(&cursor[d],1);
    csr[rowptr[d]+p] = src[i];
  }
}

// One wave (64 lanes) per node, 8 nodes per 512-thread block. lane = feature.
// h_out = relu( mean_agg(h_in) @ Wl + b + h_in @ Wr )
// Fused JK projection: partial[node] (+)= dot(h_out, wseg); last layer -> sigmoid.
// Gather: 16-deep clamped-predicated batches -> no serial tail, max MLP.
__global__ __launch_bounds__(512, 8) void k_sage(
    const float* __restrict__ hin, float* __restrict__ hout,
    const int* __restrict__ rowptr, const int* __restrict__ csr,
    const float* __restrict__ invdeg,
    const float* __restrict__ Wl, const float* __restrict__ bvec, const float* __restrict__ Wr,
    const float* __restrict__ wseg, const float* __restrict__ blin,
    float* __restrict__ partial, float* __restrict__ finout,
    int first, int nnodes)
{
  __shared__ float wl[64*64];
  __shared__ float wr[64*64];
  __shared__ float bs[64];
  __shared__ float wsg[64];
  int t=threadIdx.x;
  {
    const float4* a=(const float4*)Wl; const float4* b=(const float4*)Wr;
    float4* sa=(float4*)wl; float4* sb=(float4*)wr;
    #pragma unroll
    for(int r=0;r<2;r++){ sa[t+r*512]=a[t+r*512]; sb[t+r*512]=b[t+r*512]; }
    if(t<64){ bs[t]=bvec[t]; wsg[t]=wseg[t]; }
  }
  __syncthreads();
  int lane=t&63, wid=t>>6;
  int node=blockIdx.x*8+wid;
  if(node>=nnodes) return;
  int start=rowptr[node], end=rowptr[node+1];

  // issue self-row + invdeg early (independent of gathers)
  float hn  = hin[(size_t)node*HD+lane];
  float idg = invdeg[node];

  float acc0=0.f, acc1=0.f, acc2=0.f, acc3=0.f;
  for(int e=start; e<end; e+=16){
    int rem = end - e;                 // >= 1
    float v[16];
    #pragma unroll
    for(int i=0;i<16;i++){
      int off = (i<rem)? i : rem-1;    // clamp: dup last neighbor (same line, cheap)
      int s = csr[e+off];
      v[i] = hin[(size_t)s*HD+lane];
    }
    #pragma unroll
    for(int i=0;i<16;i++){
      float vv = (i<rem)? v[i] : 0.f;  // mask out clamped dups
      if((i&3)==0) acc0+=vv; else if((i&3)==1) acc1+=vv;
      else if((i&3)==2) acc2+=vv; else acc3+=vv;
    }
  }
  float agg = ((acc0+acc1)+(acc2+acc3)) * idg;

  float acc = bs[lane];
  #pragma unroll
  for(int k=0;k<64;k++){
    acc = fmaf(__shfl(agg,k,64), wl[k*64+lane], acc);
    acc = fmaf(__shfl(hn,k,64),  wr[k*64+lane], acc);
  }
  float r = fmaxf(acc, 0.f);
  hout[(size_t)node*HD+lane] = r;
  float c = r*wsg[lane];
  #pragma unroll
  for(int off=32; off>0; off>>=1) c += __shfl_xor(c, off, 64);
  if(lane==0){
    float p = first ? (blin[0]+c) : (partial[node]+c);
    if(finout) finout[node] = 1.0f/(1.0f+expf(-p));
    else partial[node]=p;
  }
}

extern "C" void kernel_launch(void* const* d_in, const int* in_sizes, int n_in,
                              void* d_out, int out_size, void* d_ws, size_t ws_size,
                              hipStream_t stream){
  const float* x    =(const float*)d_in[0];
  const int*   ei   =(const int*)  d_in[1];
  const float* W1l  =(const float*)d_in[2];
  const float* b1   =(const float*)d_in[3];
  const float* W1r  =(const float*)d_in[4];
  const float* W2l  =(const float*)d_in[5];
  const float* b2   =(const float*)d_in[6];
  const float* W2r  =(const float*)d_in[7];
  const float* W3l  =(const float*)d_in[8];
  const float* b3   =(const float*)d_in[9];
  const float* W3r  =(const float*)d_in[10];
  const float* Wlin =(const float*)d_in[11];
  const float* blin =(const float*)d_in[12];
  float* out=(float*)d_out;

  const int N=N_NODES, E=N_EDGES;
  char* ws=(char*)d_ws;
  size_t off=0;
  auto take=[&](size_t bytes)->char*{ char* p=ws+off; off=(off+bytes+255)&~(size_t)255; return p; };
  int*   deg      =(int*)  take((size_t)N*4);
  int*   rowptr   =(int*)  take((size_t)(N+1)*4);
  int*   cursor   =(int*)  take((size_t)N*4);
  int*   csr      =(int*)  take((size_t)E*4);
  int*   partialS =(int*)  take(512*4);
  float* invdeg   =(float*)take((size_t)N*4);
  float* hA       =(float*)take((size_t)N*HD*4);
  float* hB       =(float*)take((size_t)N*HD*4);
  float* pacc     =(float*)take((size_t)N*4);

  const int NB=(N+255)/256;           // 391
  const int EB=(E+255)/256;           // 6250

  k_zero_i32     <<<NB, 256, 0, stream>>>(deg, N);
  k_count_deg    <<<EB, 256, 0, stream>>>(ei+E, deg, E);
  k_block_sums   <<<NB, 256, 0, stream>>>(deg, partialS, N);
  k_scan_partials<<<1, 512, 0, stream>>>(partialS, NB);
  k_rowptr_invdeg<<<NB, 256, 0, stream>>>(deg, partialS, rowptr, invdeg, cursor, N, E);
  k_scatter      <<<EB, 256, 0, stream>>>(ei, ei+E, rowptr, cursor, csr, E);

  dim3 sg((N+7)/8);
  k_sage<<<sg, 512, 0, stream>>>(x,  hA, rowptr, csr, invdeg, W1l,b1,W1r, Wlin+0,   blin, pacc, (float*)nullptr, 1, N);
  k_sage<<<sg, 512, 0, stream>>>(hA, hB, rowptr, csr, invdeg, W2l,b2,W2r, Wlin+64,  blin, pacc, (float*)nullptr, 0, N);
  k_sage<<<sg, 512, 0, stream>>>(hB, hA, rowptr, csr, invdeg, W3l,b3,W3r, Wlin+128, blin, pacc, out, 0, N);
}

// Round 9
// 759.072 us; speedup vs baseline: 1.6947x; 1.0039x over previous
//
#include <hip/hip_runtime.h>
#include <math.h>

#define N_NODES 100000
#define N_EDGES 1600000
#define HD 64

typedef unsigned short ushort_t;

__device__ __forceinline__ float bf2f(ushort_t h){
  union{unsigned u; float f;} v; v.u = ((unsigned)h)<<16; return v.f;
}
__device__ __forceinline__ ushort_t f2bf(float f){
  union{float f; unsigned u;} v; v.f=f;
  unsigned b = v.u + 0x7FFF + ((v.u>>16)&1);
  return (ushort_t)(b>>16);
}

__global__ void k_zero_i32(int* __restrict__ p, int n){
  int i = blockIdx.x*blockDim.x + threadIdx.x;
  if(i<n) p[i]=0;
}

__global__ void k_count_deg(const int* __restrict__ dst, int* __restrict__ deg, int n){
  int i = blockIdx.x*blockDim.x + threadIdx.x;
  if(i<n) atomicAdd(&deg[dst[i]], 1);
}

__global__ void k_f32_to_bf16(const float* __restrict__ in, ushort_t* __restrict__ out, int n){
  int i = blockIdx.x*blockDim.x + threadIdx.x;
  int idx = i*4;
  if(idx+3<n){
    float4 v = *(const float4*)&in[idx];
    ushort_t o0=f2bf(v.x), o1=f2bf(v.y), o2=f2bf(v.z), o3=f2bf(v.w);
    ushort2 a; a.x=o0; a.y=o1;
    ushort2 b; b.x=o2; b.y=o3;
    *(ushort2*)&out[idx] = a;
    *(ushort2*)&out[idx+2] = b;
  } else {
    for(int k=idx;k<n;k++) out[k]=f2bf(in[k]);
  }
}

// per-256-chunk sums of deg -> partial[block]
__global__ void k_block_sums(const int* __restrict__ deg, int* __restrict__ partial, int n){
  __shared__ int s[256];
  int t=threadIdx.x, i=blockIdx.x*256+t;
  s[t] = (i<n)? deg[i] : 0;
  __syncthreads();
  for(int off=128; off>0; off>>=1){ if(t<off) s[t]+=s[t+off]; __syncthreads(); }
  if(t==0) partial[blockIdx.x]=s[0];
}

// exclusive scan of partial[0..nblk) in one 512-thread block (nblk<=512)
__global__ void k_scan_partials(int* __restrict__ partial, int nblk){
  __shared__ int s[512];
  int t=threadIdx.x;
  int v = (t<nblk)? partial[t] : 0;
  s[t]=v;
  __syncthreads();
  for(int off=1; off<512; off<<=1){
    int add = (t>=off)? s[t-off]:0;
    __syncthreads();
    s[t]+=add;
    __syncthreads();
  }
  if(t<nblk) partial[t] = s[t]-v;  // exclusive
}

// rowptr[i]=exclusive scan of deg; invdeg=1/max(deg,1); cursor=0; rowptr[N]=E
__global__ void k_rowptr_invdeg(const int* __restrict__ deg, const int* __restrict__ partial,
                                int* __restrict__ rowptr, float* __restrict__ invdeg,
                                int* __restrict__ cursor, int n, int ne){
  __shared__ int s[256];
  int t=threadIdx.x, i=blockIdx.x*256+t;
  int v = (i<n)? deg[i]:0;
  s[t]=v;
  __syncthreads();
  for(int off=1; off<256; off<<=1){
    int add=(t>=off)? s[t-off]:0;
    __syncthreads();
    s[t]+=add;
    __syncthreads();
  }
  if(i<n){
    rowptr[i] = partial[blockIdx.x] + s[t]-v;
    invdeg[i] = 1.0f/fmaxf((float)v,1.0f);
    cursor[i] = 0;
  }
  if(i==0) rowptr[n]=ne;
}

__global__ void k_scatter(const int* __restrict__ src, const int* __restrict__ dst,
                          const int* __restrict__ rowptr, int* __restrict__ cursor,
                          int* __restrict__ csr, int n){
  int i = blockIdx.x*blockDim.x + threadIdx.x;
  if(i<n){
    int d = dst[i];
    int p = atomicAdd(&cursor[d],1);
    csr[rowptr[d]+p] = src[i];
  }
}

// One wave per node, 8 nodes per 512-thread block.
// h stored in bf16. Lane layout: half = lane>>5, f2 = lane&31 -> lane owns
// features (2*f2, 2*f2+1). Gather processes 2 edges per load instruction
// (half 0 -> even batch slot, half 1 -> odd). Dense transform in f32 with
// weights in LDS; broadcast feature k from lane k>>1, component k&1.
__global__ __launch_bounds__(512, 8) void k_sage(
    const ushort_t* __restrict__ hin, ushort_t* __restrict__ hout,
    const int* __restrict__ rowptr, const int* __restrict__ csr,
    const float* __restrict__ invdeg,
    const float* __restrict__ Wl, const float* __restrict__ bvec, const float* __restrict__ Wr,
    const float* __restrict__ wseg, const float* __restrict__ blin,
    float* __restrict__ partial, float* __restrict__ finout,
    int first, int nnodes)
{
  __shared__ float wl[64*64];
  __shared__ float wr[64*64];
  __shared__ float bs[64];
  __shared__ float wsg[64];
  int t=threadIdx.x;
  {
    const float4* a=(const float4*)Wl; const float4* b=(const float4*)Wr;
    float4* sa=(float4*)wl; float4* sb=(float4*)wr;
    #pragma unroll
    for(int r=0;r<2;r++){ sa[t+r*512]=a[t+r*512]; sb[t+r*512]=b[t+r*512]; }
    if(t<64){ bs[t]=bvec[t]; wsg[t]=wseg[t]; }
  }
  __syncthreads();
  int lane=t&63, wid=t>>6;
  int node=blockIdx.x*8+wid;
  if(node>=nnodes) return;
  int start=rowptr[node], end=rowptr[node+1];
  int f2 = lane&31, half = lane>>5;

  // hoisted independent loads
  ushort2 hv = *(const ushort2*)&hin[(size_t)node*HD + 2*f2];
  float idg = invdeg[node];
  float hnx = bf2f(hv.x), hny = bf2f(hv.y);

  float ax=0.f, ay=0.f;
  for(int e=start; e<end; e+=16){
    ushort2 v[8];
    #pragma unroll
    for(int j=0;j<8;j++){
      int idx = e + 2*j + half;
      int cidx = idx < end ? idx : end-1;   // clamp (same line as last, cheap)
      int s = csr[cidx];
      v[j] = *(const ushort2*)&hin[(size_t)s*HD + 2*f2];
    }
    #pragma unroll
    for(int j=0;j<8;j++){
      int idx = e + 2*j + half;
      float m = idx < end ? 1.f : 0.f;      // mask clamped dups
      ax = fmaf(m, bf2f(v[j].x), ax);
      ay = fmaf(m, bf2f(v[j].y), ay);
    }
  }
  // combine the two half-wave partial sums (halves covered interleaved edges)
  ax += __shfl_xor(ax, 32, 64);
  ay += __shfl_xor(ay, 32, 64);
  float agx = ax*idg, agy = ay*idg;

  float acc = bs[lane];
  #pragma unroll
  for(int k=0;k<64;k++){
    float a = __shfl((k&1)? agy : agx, k>>1, 64);
    float h = __shfl((k&1)? hny : hnx, k>>1, 64);
    acc = fmaf(a, wl[k*64+lane], acc);
    acc = fmaf(h, wr[k*64+lane], acc);
  }
  float r = fmaxf(acc, 0.f);
  if(!finout) hout[(size_t)node*HD+lane] = f2bf(r);
  float c = r*wsg[lane];
  #pragma unroll
  for(int off=32; off>0; off>>=1) c += __shfl_xor(c, off, 64);
  if(lane==0){
    float p = first ? (blin[0]+c) : (partial[node]+c);
    if(finout) finout[node] = 1.0f/(1.0f+expf(-p));
    else partial[node]=p;
  }
}

extern "C" void kernel_launch(void* const* d_in, const int* in_sizes, int n_in,
                              void* d_out, int out_size, void* d_ws, size_t ws_size,
                              hipStream_t stream){
  const float* x    =(const float*)d_in[0];
  const int*   ei   =(const int*)  d_in[1];
  const float* W1l  =(const float*)d_in[2];
  const float* b1   =(const float*)d_in[3];
  const float* W1r  =(const float*)d_in[4];
  const float* W2l  =(const float*)d_in[5];
  const float* b2   =(const float*)d_in[6];
  const float* W2r  =(const float*)d_in[7];
  const float* W3l  =(const float*)d_in[8];
  const float* b3   =(const float*)d_in[9];
  const float* W3r  =(const float*)d_in[10];
  const float* Wlin =(const float*)d_in[11];
  const float* blin =(const float*)d_in[12];
  float* out=(float*)d_out;

  const int N=N_NODES, E=N_EDGES;
  char* ws=(char*)d_ws;
  size_t off=0;
  auto take=[&](size_t bytes)->char*{ char* p=ws+off; off=(off+bytes+255)&~(size_t)255; return p; };
  int*      deg      =(int*)     take((size_t)N*4);
  int*      rowptr   =(int*)     take((size_t)(N+1)*4);
  int*      cursor   =(int*)     take((size_t)N*4);
  int*      csr      =(int*)     take((size_t)E*4);
  int*      partialS =(int*)     take(512*4);
  float*    invdeg   =(float*)   take((size_t)N*4);
  ushort_t* xbf      =(ushort_t*)take((size_t)N*HD*2);
  ushort_t* hbfA     =(ushort_t*)take((size_t)N*HD*2);
  ushort_t* hbfB     =(ushort_t*)take((size_t)N*HD*2);
  float*    pacc     =(float*)   take((size_t)N*4);

  const int NB=(N+255)/256;           // 391
  const int EB=(E+255)/256;           // 6250
  const int CB=(N*HD/4+255)/256;      // bf16 convert blocks (6.4M elems /4)

  k_zero_i32     <<<NB, 256, 0, stream>>>(deg, N);
  k_count_deg    <<<EB, 256, 0, stream>>>(ei+E, deg, E);
  k_f32_to_bf16  <<<CB, 256, 0, stream>>>(x, xbf, N*HD);
  k_block_sums   <<<NB, 256, 0, stream>>>(deg, partialS, N);
  k_scan_partials<<<1, 512, 0, stream>>>(partialS, NB);
  k_rowptr_invdeg<<<NB, 256, 0, stream>>>(deg, partialS, rowptr, invdeg, cursor, N, E);
  k_scatter      <<<EB, 256, 0, stream>>>(ei, ei+E, rowptr, cursor, csr, E);

  dim3 sg((N+7)/8);
  k_sage<<<sg, 512, 0, stream>>>(xbf,  hbfA, rowptr, csr, invdeg, W1l,b1,W1r, Wlin+0,   blin, pacc, (float*)nullptr, 1, N);
  k_sage<<<sg, 512, 0, stream>>>(hbfA, hbfB, rowptr, csr, invdeg, W2l,b2,W2r, Wlin+64,  blin, pacc, (float*)nullptr, 0, N);
  k_sage<<<sg, 512, 0, stream>>>(hbfB, hbfA, rowptr, csr, invdeg, W3l,b3,W3r, Wlin+128, blin, pacc, out, 0, N);
}

// Round 10
// 407.340 us; speedup vs baseline: 3.1580x; 1.8635x over previous
//
#include <hip/hip_runtime.h>
#include <math.h>

#define N_NODES 100000
#define N_EDGES 1600000
#define HD 64
#define TILE 128

typedef unsigned short ushort_t;
typedef __attribute__((ext_vector_type(8))) unsigned short ushort8_t;
typedef __attribute__((ext_vector_type(4))) unsigned short ushort4_t;

__device__ __forceinline__ float bf2f(ushort_t h){
  union{unsigned u; float f;} v; v.u = ((unsigned)h)<<16; return v.f;
}
__device__ __forceinline__ ushort_t f2bf(float f){
  union{float f; unsigned u;} v; v.f=f;
  unsigned b = v.u + 0x7FFF + ((v.u>>16)&1);
  return (ushort_t)(b>>16);
}

__global__ void k_zero_i32(int* __restrict__ p, int n){
  int i = blockIdx.x*blockDim.x + threadIdx.x;
  if(i<n) p[i]=0;
}

__global__ void k_count_deg(const int* __restrict__ dst, int* __restrict__ deg, int n){
  int i = blockIdx.x*blockDim.x + threadIdx.x;
  if(i<n) atomicAdd(&deg[dst[i]], 1);
}

__global__ void k_f32_to_bf16(const float* __restrict__ in, ushort_t* __restrict__ out, int n){
  int i = blockIdx.x*blockDim.x + threadIdx.x;
  int idx = i*4;
  if(idx+3<n){
    float4 v = *(const float4*)&in[idx];
    ushort_t o0=f2bf(v.x), o1=f2bf(v.y), o2=f2bf(v.z), o3=f2bf(v.w);
    ushort2 a; a.x=o0; a.y=o1;
    ushort2 b; b.x=o2; b.y=o3;
    *(ushort2*)&out[idx] = a;
    *(ushort2*)&out[idx+2] = b;
  } else {
    for(int k=idx;k<n;k++) out[k]=f2bf(in[k]);
  }
}

// per-256-chunk sums of deg -> partial[block]
__global__ void k_block_sums(const int* __restrict__ deg, int* __restrict__ partial, int n){
  __shared__ int s[256];
  int t=threadIdx.x, i=blockIdx.x*256+t;
  s[t] = (i<n)? deg[i] : 0;
  __syncthreads();
  for(int off=128; off>0; off>>=1){ if(t<off) s[t]+=s[t+off]; __syncthreads(); }
  if(t==0) partial[blockIdx.x]=s[0];
}

// exclusive scan of partial[0..nblk) in one 512-thread block (nblk<=512)
__global__ void k_scan_partials(int* __restrict__ partial, int nblk){
  __shared__ int s[512];
  int t=threadIdx.x;
  int v = (t<nblk)? partial[t] : 0;
  s[t]=v;
  __syncthreads();
  for(int off=1; off<512; off<<=1){
    int add = (t>=off)? s[t-off]:0;
    __syncthreads();
    s[t]+=add;
    __syncthreads();
  }
  if(t<nblk) partial[t] = s[t]-v;  // exclusive
}

// rowptr[i]=exclusive scan of deg; invdeg=1/max(deg,1); cursor=0; rowptr[N]=E
__global__ void k_rowptr_invdeg(const int* __restrict__ deg, const int* __restrict__ partial,
                                int* __restrict__ rowptr, float* __restrict__ invdeg,
                                int* __restrict__ cursor, int n, int ne){
  __shared__ int s[256];
  int t=threadIdx.x, i=blockIdx.x*256+t;
  int v = (i<n)? deg[i]:0;
  s[t]=v;
  __syncthreads();
  for(int off=1; off<256; off<<=1){
    int add=(t>=off)? s[t-off]:0;
    __syncthreads();
    s[t]+=add;
    __syncthreads();
  }
  if(i<n){
    rowptr[i] = partial[blockIdx.x] + s[t]-v;
    invdeg[i] = 1.0f/fmaxf((float)v,1.0f);
    cursor[i] = 0;
  }
  if(i==0) rowptr[n]=ne;
}

__global__ void k_scatter(const int* __restrict__ src, const int* __restrict__ dst,
                          const int* __restrict__ rowptr, int* __restrict__ cursor,
                          int* __restrict__ csr, int n){
  int i = blockIdx.x*blockDim.x + threadIdx.x;
  if(i<n){
    int d = dst[i];
    int p = atomicAdd(&cursor[d],1);
    csr[rowptr[d]+p] = src[i];
  }
}

// Pure gather: one wave per node. Lane layout: slot = lane>>3 (8 edge slots),
// c = lane&7 (feature chunk c*8..c*8+7, 16B per lane). One VMEM instruction
// gathers 8 edges (8 scattered 128B rows); two sub-batches issued back-to-back
// -> 16 rows in flight per wave. Output: agg[node] = mean of neighbor rows, bf16.
__global__ __launch_bounds__(512) void k_gather(
    const ushort_t* __restrict__ hin, ushort_t* __restrict__ agg,
    const int* __restrict__ rowptr, const int* __restrict__ csr,
    const float* __restrict__ invdeg, int nnodes)
{
  int t=threadIdx.x;
  int lane=t&63, wid=t>>6;
  int node=blockIdx.x*8+wid;
  if(node>=nnodes) return;
  int start=rowptr[node], end=rowptr[node+1];
  int slot = lane>>3;
  int c    = lane&7;
  float idg = invdeg[node];
  float acc[8]={0,0,0,0,0,0,0,0};
  for(int e=start; e<end; e+=16){
    int i1 = e + slot, i2 = e + 8 + slot;
    int c1 = i1<end ? i1 : end-1;
    int c2 = i2<end ? i2 : end-1;
    int s1 = csr[c1], s2 = csr[c2];
    ushort8_t v1 = *(const ushort8_t*)&hin[(size_t)s1*HD + c*8];
    ushort8_t v2 = *(const ushort8_t*)&hin[(size_t)s2*HD + c*8];
    float m1 = i1<end ? 1.f : 0.f;
    float m2 = i2<end ? 1.f : 0.f;
    #pragma unroll
    for(int j=0;j<8;j++){
      acc[j] = fmaf(m1, bf2f(v1[j]), acc[j]);
      acc[j] = fmaf(m2, bf2f(v2[j]), acc[j]);
    }
  }
  // reduce across the 8 edge slots (lane bits 3,4,5)
  #pragma unroll
  for(int off=8; off<64; off<<=1){
    #pragma unroll
    for(int j=0;j<8;j++) acc[j] += __shfl_xor(acc[j], off, 64);
  }
  if(slot==0){
    ushort8_t o;
    #pragma unroll
    for(int j=0;j<8;j++) o[j] = f2bf(acc[j]*idg);
    *(ushort8_t*)&agg[(size_t)node*HD + c*8] = o;
  }
}

// Register-tiled dense: out = relu([agg|h] @ [Wl;Wr] + b), fused JK dot (+sigmoid).
// Block = 256 threads, 128 nodes. Thread (g=t>>5, nl=t&31) computes
// nodes {nl, nl+32, nl+64, nl+96} x outputs {g*8..g*8+7}.
// sA row stride 134 u16 (odd word stride -> conflict-free column reads).
__global__ __launch_bounds__(256) void k_dense(
    const ushort_t* __restrict__ hin, const ushort_t* __restrict__ agg,
    ushort_t* __restrict__ hout,
    const float* __restrict__ Wl, const float* __restrict__ bvec, const float* __restrict__ Wr,
    const float* __restrict__ wseg, const float* __restrict__ blin,
    float* __restrict__ partial, float* __restrict__ finout,
    int first, int nnodes)
{
  __shared__ ushort_t sA[TILE][134];   // [node][k], k<64: agg, k>=64: h
  __shared__ ushort_t sW[128][72];     // [k][j] bf16, row 144B (16B aligned)
  __shared__ float sB[64], sS[64];
  __shared__ float sJKp[8][TILE];
  int t = threadIdx.x;
  int n0 = blockIdx.x*TILE;

  // stage A-tile: thread -> (node_local = t>>1, half = t&1); 8x16B global loads,
  // 4B LDS writes (odd row stride forbids b128 LDS writes)
  {
    int nl = t>>1, half = t&1;
    int n = n0 + nl;
    const ushort_t* srcp = half ? hin : agg;
    #pragma unroll
    for(int j=0;j<8;j++){
      uint4 v = make_uint4(0u,0u,0u,0u);
      if(n < nnodes) v = *(const uint4*)&srcp[(size_t)n*HD + j*8];
      uint* dstp = (uint*)&sA[nl][half*64 + j*8];
      dstp[0]=v.x; dstp[1]=v.y; dstp[2]=v.z; dstp[3]=v.w;
    }
  }
  // stage W: 8192 f32 -> bf16
  #pragma unroll
  for(int r=0;r<8;r++){
    int elem = r*1024 + t*4;
    int k = elem>>6, j = elem&63;
    const float* srcw = (k<64) ? &Wl[k*64+j] : &Wr[(k-64)*64+j];
    float4 w = *(const float4*)srcw;
    ushort4_t o; o[0]=f2bf(w.x); o[1]=f2bf(w.y); o[2]=f2bf(w.z); o[3]=f2bf(w.w);
    *(ushort4_t*)&sW[k][j] = o;
  }
  if(t<64){ sB[t]=bvec[t]; sS[t]=wseg[t]; }
  __syncthreads();

  int g = t>>5, nl = t&31;
  float acc[4][8];
  #pragma unroll
  for(int i=0;i<4;i++)
    #pragma unroll
    for(int j=0;j<8;j++) acc[i][j]=0.f;

  for(int k=0;k<128;k++){
    float a0 = bf2f(sA[nl   ][k]);
    float a1 = bf2f(sA[nl+32][k]);
    float a2 = bf2f(sA[nl+64][k]);
    float a3 = bf2f(sA[nl+96][k]);
    ushort8_t wv = *(const ushort8_t*)&sW[k][g*8];
    #pragma unroll
    for(int j=0;j<8;j++){
      float w = bf2f(wv[j]);
      acc[0][j] = fmaf(a0,w,acc[0][j]);
      acc[1][j] = fmaf(a1,w,acc[1][j]);
      acc[2][j] = fmaf(a2,w,acc[2][j]);
      acc[3][j] = fmaf(a3,w,acc[3][j]);
    }
  }

  #pragma unroll
  for(int i=0;i<4;i++){
    int nlc = nl + i*32;
    int n = n0 + nlc;
    float p = 0.f;
    ushort8_t o;
    #pragma unroll
    for(int j=0;j<8;j++){
      float r = fmaxf(acc[i][j] + sB[g*8+j], 0.f);
      p = fmaf(r, sS[g*8+j], p);
      o[j] = f2bf(r);
    }
    if(!finout && n<nnodes) *(ushort8_t*)&hout[(size_t)n*HD + g*8] = o;
    sJKp[g][nlc] = p;
  }
  __syncthreads();
  if(t < TILE){
    int n = n0 + t;
    if(n < nnodes){
      float ssum = 0.f;
      #pragma unroll
      for(int gg=0; gg<8; gg++) ssum += sJKp[gg][t];
      float p = first ? (blin[0] + ssum) : (partial[n] + ssum);
      if(finout) finout[n] = 1.0f/(1.0f+expf(-p));
      else partial[n] = p;
    }
  }
}

extern "C" void kernel_launch(void* const* d_in, const int* in_sizes, int n_in,
                              void* d_out, int out_size, void* d_ws, size_t ws_size,
                              hipStream_t stream){
  const float* x    =(const float*)d_in[0];
  const int*   ei   =(const int*)  d_in[1];
  const float* W1l  =(const float*)d_in[2];
  const float* b1   =(const float*)d_in[3];
  const float* W1r  =(const float*)d_in[4];
  const float* W2l  =(const float*)d_in[5];
  const float* b2   =(const float*)d_in[6];
  const float* W2r  =(const float*)d_in[7];
  const float* W3l  =(const float*)d_in[8];
  const float* b3   =(const float*)d_in[9];
  const float* W3r  =(const float*)d_in[10];
  const float* Wlin =(const float*)d_in[11];
  const float* blin =(const float*)d_in[12];
  float* out=(float*)d_out;

  const int N=N_NODES, E=N_EDGES;
  char* ws=(char*)d_ws;
  size_t off=0;
  auto take=[&](size_t bytes)->char*{ char* p=ws+off; off=(off+bytes+255)&~(size_t)255; return p; };
  int*      deg      =(int*)     take((size_t)N*4);
  int*      rowptr   =(int*)     take((size_t)(N+1)*4);
  int*      cursor   =(int*)     take((size_t)N*4);
  int*      csr      =(int*)     take((size_t)E*4);
  int*      partialS =(int*)     take(512*4);
  float*    invdeg   =(float*)   take((size_t)N*4);
  ushort_t* xbf      =(ushort_t*)take((size_t)N*HD*2);
  ushort_t* hbfA     =(ushort_t*)take((size_t)N*HD*2);
  ushort_t* hbfB     =(ushort_t*)take((size_t)N*HD*2);
  ushort_t* aggbf    =(ushort_t*)take((size_t)N*HD*2);
  float*    pacc     =(float*)   take((size_t)N*4);

  const int NB=(N+255)/256;           // 391
  const int EB=(E+255)/256;           // 6250
  const int CB=(N*HD/4+255)/256;      // bf16 convert blocks

  k_zero_i32     <<<NB, 256, 0, stream>>>(deg, N);
  k_count_deg    <<<EB, 256, 0, stream>>>(ei+E, deg, E);
  k_f32_to_bf16  <<<CB, 256, 0, stream>>>(x, xbf, N*HD);
  k_block_sums   <<<NB, 256, 0, stream>>>(deg, partialS, N);
  k_scan_partials<<<1, 512, 0, stream>>>(partialS, NB);
  k_rowptr_invdeg<<<NB, 256, 0, stream>>>(deg, partialS, rowptr, invdeg, cursor, N, E);
  k_scatter      <<<EB, 256, 0, stream>>>(ei, ei+E, rowptr, cursor, csr, E);

  dim3 gg((N+7)/8);                   // 12500 blocks x 512
  dim3 gd((N+TILE-1)/TILE);           // 782 blocks x 256

  // layer 1
  k_gather<<<gg, 512, 0, stream>>>(xbf, aggbf, rowptr, csr, invdeg, N);
  k_dense <<<gd, 256, 0, stream>>>(xbf, aggbf, hbfA, W1l,b1,W1r, Wlin+0,  blin, pacc, (float*)nullptr, 1, N);
  // layer 2
  k_gather<<<gg, 512, 0, stream>>>(hbfA, aggbf, rowptr, csr, invdeg, N);
  k_dense <<<gd, 256, 0, stream>>>(hbfA, aggbf, hbfB, W2l,b2,W2r, Wlin+64, blin, pacc, (float*)nullptr, 0, N);
  // layer 3
  k_gather<<<gg, 512, 0, stream>>>(hbfB, aggbf, rowptr, csr, invdeg, N);
  k_dense <<<gd, 256, 0, stream>>>(hbfB, aggbf, hbfA, W3l,b3,W3r, Wlin+128, blin, pacc, out, 0, N);
}

// Round 11
// 381.880 us; speedup vs baseline: 3.3686x; 1.0667x over previous
//
#include <hip/hip_runtime.h>
#include <math.h>

#define N_NODES 100000
#define N_EDGES 1600000
#define HD 64
#define TILE 128
#define NBUCK 128          // dst>>10 -> 98 used buckets
#define EPB 4096           // edges per block in hist/reorder

typedef unsigned short ushort_t;
typedef __attribute__((ext_vector_type(8))) unsigned short ushort8_t;
typedef __attribute__((ext_vector_type(4))) unsigned short ushort4_t;

__device__ __forceinline__ float bf2f(ushort_t h){
  union{unsigned u; float f;} v; v.u = ((unsigned)h)<<16; return v.f;
}
__device__ __forceinline__ ushort_t f2bf(float f){
  union{float f; unsigned u;} v; v.f=f;
  unsigned b = v.u + 0x7FFF + ((v.u>>16)&1);
  return (ushort_t)(b>>16);
}

__global__ void k_zero_i32(int* __restrict__ p, int n){
  int i = blockIdx.x*blockDim.x + threadIdx.x;
  if(i<n) p[i]=0;
}

__global__ void k_f32_to_bf16(const float* __restrict__ in, ushort_t* __restrict__ out, int n){
  int i = blockIdx.x*blockDim.x + threadIdx.x;
  int idx = i*4;
  if(idx+3<n){
    float4 v = *(const float4*)&in[idx];
    ushort2 a; a.x=f2bf(v.x); a.y=f2bf(v.y);
    ushort2 b; b.x=f2bf(v.z); b.y=f2bf(v.w);
    *(ushort2*)&out[idx] = a;
    *(ushort2*)&out[idx+2] = b;
  } else {
    for(int k=idx;k<n;k++) out[k]=f2bf(in[k]);
  }
}

// ---- CSR build: coarse radix partition by dst>>10 then fine scatter ----

__global__ __launch_bounds__(512) void k_hist(const int* __restrict__ dst, int* __restrict__ bcnt, int n){
  __shared__ int lh[NBUCK];
  int t=threadIdx.x;
  if(t<NBUCK) lh[t]=0;
  __syncthreads();
  int base = blockIdx.x*EPB;
  #pragma unroll
  for(int j=0;j<8;j++){
    int e = base + t + j*512;
    if(e<n) atomicAdd(&lh[dst[e]>>10], 1);
  }
  __syncthreads();
  if(t<NBUCK && lh[t]) atomicAdd(&bcnt[t], lh[t]);
}

__global__ void k_scan128(const int* __restrict__ bcnt, int* __restrict__ gcur){
  __shared__ int s[NBUCK];
  int t=threadIdx.x;
  int v=bcnt[t]; s[t]=v;
  __syncthreads();
  for(int off=1; off<NBUCK; off<<=1){
    int a=(t>=off)? s[t-off]:0;
    __syncthreads();
    s[t]+=a;
    __syncthreads();
  }
  gcur[t]=s[t]-v;   // exclusive base; used as running cursor by k_reorder
}

__global__ __launch_bounds__(512) void k_reorder(
    const int* __restrict__ src, const int* __restrict__ dst,
    int* __restrict__ gcur, int2* __restrict__ pairs, int n){
  __shared__ int lh[NBUCK];
  __shared__ int lbase[NBUCK];
  int t=threadIdx.x;
  if(t<NBUCK) lh[t]=0;
  __syncthreads();
  int base = blockIdx.x*EPB;
  int bb[8], rr[8], sv[8], dv[8];
  #pragma unroll
  for(int j=0;j<8;j++){
    int e = base + t + j*512;
    if(e<n){
      int d=dst[e];
      int b=d>>10;
      rr[j]=atomicAdd(&lh[b],1);
      bb[j]=b; sv[j]=src[e]; dv[j]=d;
    } else bb[j]=-1;
  }
  __syncthreads();
  if(t<NBUCK && lh[t]) lbase[t]=atomicAdd(&gcur[t], lh[t]);
  __syncthreads();
  #pragma unroll
  for(int j=0;j<8;j++){
    if(bb[j]>=0){
      int pos = lbase[bb[j]] + rr[j];
      pairs[pos] = make_int2(sv[j], dv[j]);
    }
  }
}

__global__ void k_count2(const int2* __restrict__ pairs, int* __restrict__ deg, int n){
  int i = blockIdx.x*blockDim.x + threadIdx.x;
  if(i<n) atomicAdd(&deg[pairs[i].y], 1);
}

__global__ void k_scatter2(const int2* __restrict__ pairs,
                           const int* __restrict__ rowptr, int* __restrict__ cursor,
                           int* __restrict__ csr, int n){
  int i = blockIdx.x*blockDim.x + threadIdx.x;
  if(i<n){
    int2 p = pairs[i];
    int pos = atomicAdd(&cursor[p.y],1);
    csr[rowptr[p.y]+pos] = p.x;
  }
}

// per-256-chunk sums of deg -> partial[block]
__global__ void k_block_sums(const int* __restrict__ deg, int* __restrict__ partial, int n){
  __shared__ int s[256];
  int t=threadIdx.x, i=blockIdx.x*256+t;
  s[t] = (i<n)? deg[i] : 0;
  __syncthreads();
  for(int off=128; off>0; off>>=1){ if(t<off) s[t]+=s[t+off]; __syncthreads(); }
  if(t==0) partial[blockIdx.x]=s[0];
}

// exclusive scan of partial[0..nblk) in one 512-thread block (nblk<=512)
__global__ void k_scan_partials(int* __restrict__ partial, int nblk){
  __shared__ int s[512];
  int t=threadIdx.x;
  int v = (t<nblk)? partial[t] : 0;
  s[t]=v;
  __syncthreads();
  for(int off=1; off<512; off<<=1){
    int add = (t>=off)? s[t-off]:0;
    __syncthreads();
    s[t]+=add;
    __syncthreads();
  }
  if(t<nblk) partial[t] = s[t]-v;  // exclusive
}

// rowptr[i]=exclusive scan of deg; invdeg=1/max(deg,1); cursor=0; rowptr[N]=E
__global__ void k_rowptr_invdeg(const int* __restrict__ deg, const int* __restrict__ partial,
                                int* __restrict__ rowptr, float* __restrict__ invdeg,
                                int* __restrict__ cursor, int n, int ne){
  __shared__ int s[256];
  int t=threadIdx.x, i=blockIdx.x*256+t;
  int v = (i<n)? deg[i]:0;
  s[t]=v;
  __syncthreads();
  for(int off=1; off<256; off<<=1){
    int add=(t>=off)? s[t-off]:0;
    __syncthreads();
    s[t]+=add;
    __syncthreads();
  }
  if(i<n){
    rowptr[i] = partial[blockIdx.x] + s[t]-v;
    invdeg[i] = 1.0f/fmaxf((float)v,1.0f);
    cursor[i] = 0;
  }
  if(i==0) rowptr[n]=ne;
}

// Pure gather: one wave per node. slot = lane>>3 (8 edge slots), c = lane&7
// (16B feature chunk). One VMEM instruction gathers 8 edges; 16 rows in
// flight per wave. agg[node] = mean of neighbor rows, bf16.
__global__ __launch_bounds__(512) void k_gather(
    const ushort_t* __restrict__ hin, ushort_t* __restrict__ agg,
    const int* __restrict__ rowptr, const int* __restrict__ csr,
    const float* __restrict__ invdeg, int nnodes)
{
  int t=threadIdx.x;
  int lane=t&63, wid=t>>6;
  int node=blockIdx.x*8+wid;
  if(node>=nnodes) return;
  int start=rowptr[node], end=rowptr[node+1];
  int slot = lane>>3;
  int c    = lane&7;
  float idg = invdeg[node];
  float acc[8]={0,0,0,0,0,0,0,0};
  for(int e=start; e<end; e+=16){
    int i1 = e + slot, i2 = e + 8 + slot;
    int c1 = i1<end ? i1 : end-1;
    int c2 = i2<end ? i2 : end-1;
    int s1 = csr[c1], s2 = csr[c2];
    ushort8_t v1 = *(const ushort8_t*)&hin[(size_t)s1*HD + c*8];
    ushort8_t v2 = *(const ushort8_t*)&hin[(size_t)s2*HD + c*8];
    float m1 = i1<end ? 1.f : 0.f;
    float m2 = i2<end ? 1.f : 0.f;
    #pragma unroll
    for(int j=0;j<8;j++){
      acc[j] = fmaf(m1, bf2f(v1[j]), acc[j]);
      acc[j] = fmaf(m2, bf2f(v2[j]), acc[j]);
    }
  }
  #pragma unroll
  for(int off=8; off<64; off<<=1){
    #pragma unroll
    for(int j=0;j<8;j++) acc[j] += __shfl_xor(acc[j], off, 64);
  }
  if(slot==0){
    ushort8_t o;
    #pragma unroll
    for(int j=0;j<8;j++) o[j] = f2bf(acc[j]*idg);
    *(ushort8_t*)&agg[(size_t)node*HD + c*8] = o;
  }
}

// Register-tiled dense: out = relu([agg|h] @ [Wl;Wr] + b), fused JK dot (+sigmoid).
__global__ __launch_bounds__(256) void k_dense(
    const ushort_t* __restrict__ hin, const ushort_t* __restrict__ agg,
    ushort_t* __restrict__ hout,
    const float* __restrict__ Wl, const float* __restrict__ bvec, const float* __restrict__ Wr,
    const float* __restrict__ wseg, const float* __restrict__ blin,
    float* __restrict__ partial, float* __restrict__ finout,
    int first, int nnodes)
{
  __shared__ ushort_t sA[TILE][134];
  __shared__ ushort_t sW[128][72];
  __shared__ float sB[64], sS[64];
  __shared__ float sJKp[8][TILE];
  int t = threadIdx.x;
  int n0 = blockIdx.x*TILE;

  {
    int nl = t>>1, half = t&1;
    int n = n0 + nl;
    const ushort_t* srcp = half ? hin : agg;
    #pragma unroll
    for(int j=0;j<8;j++){
      uint4 v = make_uint4(0u,0u,0u,0u);
      if(n < nnodes) v = *(const uint4*)&srcp[(size_t)n*HD + j*8];
      uint* dstp = (uint*)&sA[nl][half*64 + j*8];
      dstp[0]=v.x; dstp[1]=v.y; dstp[2]=v.z; dstp[3]=v.w;
    }
  }
  #pragma unroll
  for(int r=0;r<8;r++){
    int elem = r*1024 + t*4;
    int k = elem>>6, j = elem&63;
    const float* srcw = (k<64) ? &Wl[k*64+j] : &Wr[(k-64)*64+j];
    float4 w = *(const float4*)srcw;
    ushort4_t o; o[0]=f2bf(w.x); o[1]=f2bf(w.y); o[2]=f2bf(w.z); o[3]=f2bf(w.w);
    *(ushort4_t*)&sW[k][j] = o;
  }
  if(t<64){ sB[t]=bvec[t]; sS[t]=wseg[t]; }
  __syncthreads();

  int g = t>>5, nl = t&31;
  float acc[4][8];
  #pragma unroll
  for(int i=0;i<4;i++)
    #pragma unroll
    for(int j=0;j<8;j++) acc[i][j]=0.f;

  for(int k=0;k<128;k++){
    float a0 = bf2f(sA[nl   ][k]);
    float a1 = bf2f(sA[nl+32][k]);
    float a2 = bf2f(sA[nl+64][k]);
    float a3 = bf2f(sA[nl+96][k]);
    ushort8_t wv = *(const ushort8_t*)&sW[k][g*8];
    #pragma unroll
    for(int j=0;j<8;j++){
      float w = bf2f(wv[j]);
      acc[0][j] = fmaf(a0,w,acc[0][j]);
      acc[1][j] = fmaf(a1,w,acc[1][j]);
      acc[2][j] = fmaf(a2,w,acc[2][j]);
      acc[3][j] = fmaf(a3,w,acc[3][j]);
    }
  }

  #pragma unroll
  for(int i=0;i<4;i++){
    int nlc = nl + i*32;
    int n = n0 + nlc;
    float p = 0.f;
    ushort8_t o;
    #pragma unroll
    for(int j=0;j<8;j++){
      float r = fmaxf(acc[i][j] + sB[g*8+j], 0.f);
      p = fmaf(r, sS[g*8+j], p);
      o[j] = f2bf(r);
    }
    if(!finout && n<nnodes) *(ushort8_t*)&hout[(size_t)n*HD + g*8] = o;
    sJKp[g][nlc] = p;
  }
  __syncthreads();
  if(t < TILE){
    int n = n0 + t;
    if(n < nnodes){
      float ssum = 0.f;
      #pragma unroll
      for(int gg=0; gg<8; gg++) ssum += sJKp[gg][t];
      float p = first ? (blin[0] + ssum) : (partial[n] + ssum);
      if(finout) finout[n] = 1.0f/(1.0f+expf(-p));
      else partial[n] = p;
    }
  }
}

extern "C" void kernel_launch(void* const* d_in, const int* in_sizes, int n_in,
                              void* d_out, int out_size, void* d_ws, size_t ws_size,
                              hipStream_t stream){
  const float* x    =(const float*)d_in[0];
  const int*   ei   =(const int*)  d_in[1];
  const float* W1l  =(const float*)d_in[2];
  const float* b1   =(const float*)d_in[3];
  const float* W1r  =(const float*)d_in[4];
  const float* W2l  =(const float*)d_in[5];
  const float* b2   =(const float*)d_in[6];
  const float* W2r  =(const float*)d_in[7];
  const float* W3l  =(const float*)d_in[8];
  const float* b3   =(const float*)d_in[9];
  const float* W3r  =(const float*)d_in[10];
  const float* Wlin =(const float*)d_in[11];
  const float* blin =(const float*)d_in[12];
  float* out=(float*)d_out;

  const int N=N_NODES, E=N_EDGES;
  char* ws=(char*)d_ws;
  size_t off=0;
  auto take=[&](size_t bytes)->char*{ char* p=ws+off; off=(off+bytes+255)&~(size_t)255; return p; };
  int*      zr       =(int*)     take((size_t)(N+NBUCK)*4);  // deg | bcnt (zeroed together)
  int*      deg      = zr;
  int*      bcnt     = zr + N;
  int*      gcur     =(int*)     take((size_t)NBUCK*4);
  int*      rowptr   =(int*)     take((size_t)(N+1)*4);
  int*      cursor   =(int*)     take((size_t)N*4);
  int*      csr      =(int*)     take((size_t)E*4);
  int2*     pairs    =(int2*)    take((size_t)E*8);
  int*      partialS =(int*)     take(512*4);
  float*    invdeg   =(float*)   take((size_t)N*4);
  ushort_t* xbf      =(ushort_t*)take((size_t)N*HD*2);
  ushort_t* hbfA     =(ushort_t*)take((size_t)N*HD*2);
  ushort_t* hbfB     =(ushort_t*)take((size_t)N*HD*2);
  ushort_t* aggbf    =(ushort_t*)take((size_t)N*HD*2);
  float*    pacc     =(float*)   take((size_t)N*4);

  const int NB=(N+255)/256;             // 391
  const int EB=(E+255)/256;             // 6250
  const int RB=(E+EPB-1)/EPB;           // 391 (hist/reorder)
  const int CB=(N*HD/4+255)/256;        // bf16 convert blocks

  k_zero_i32     <<<(N+NBUCK+255)/256, 256, 0, stream>>>(zr, N+NBUCK);
  k_f32_to_bf16  <<<CB, 256, 0, stream>>>(x, xbf, N*HD);
  k_hist         <<<RB, 512, 0, stream>>>(ei+E, bcnt, E);
  k_scan128      <<<1, NBUCK, 0, stream>>>(bcnt, gcur);
  k_reorder      <<<RB, 512, 0, stream>>>(ei, ei+E, gcur, pairs, E);
  k_count2       <<<EB, 256, 0, stream>>>(pairs, deg, E);
  k_block_sums   <<<NB, 256, 0, stream>>>(deg, partialS, N);
  k_scan_partials<<<1, 512, 0, stream>>>(partialS, NB);
  k_rowptr_invdeg<<<NB, 256, 0, stream>>>(deg, partialS, rowptr, invdeg, cursor, N, E);
  k_scatter2     <<<EB, 256, 0, stream>>>(pairs, rowptr, cursor, csr, E);

  dim3 gg((N+7)/8);
  dim3 gd((N+TILE-1)/TILE);

  k_gather<<<gg, 512, 0, stream>>>(xbf, aggbf, rowptr, csr, invdeg, N);
  k_dense <<<gd, 256, 0, stream>>>(xbf, aggbf, hbfA, W1l,b1,W1r, Wlin+0,  blin, pacc, (float*)nullptr, 1, N);
  k_gather<<<gg, 512, 0, stream>>>(hbfA, aggbf, rowptr, csr, invdeg, N);
  k_dense <<<gd, 256, 0, stream>>>(hbfA, aggbf, hbfB, W2l,b2,W2r, Wlin+64, blin, pacc, (float*)nullptr, 0, N);
  k_gather<<<gg, 512, 0, stream>>>(hbfB, aggbf, rowptr, csr, invdeg, N);
  k_dense <<<gd, 256, 0, stream>>>(hbfB, aggbf, hbfA, W3l,b3,W3r, Wlin+128, blin, pacc, out, 0, N);
}

// Round 12
// 304.707 us; speedup vs baseline: 4.2217x; 1.2533x over previous
//
#include <hip/hip_runtime.h>
#include <math.h>

#define N_NODES 100000
#define N_EDGES 1600000
#define HD 64
#define TILE 128
#define NBUCK 128          // dst>>10 -> 98 used buckets
#define BNODES 1024
#define EPB 4096           // edges per block in hist/reorder

typedef unsigned short ushort_t;
typedef __attribute__((ext_vector_type(8))) unsigned short ushort8_t;
typedef __attribute__((ext_vector_type(4))) unsigned short ushort4_t;

__device__ __forceinline__ float bf2f(ushort_t h){
  union{unsigned u; float f;} v; v.u = ((unsigned)h)<<16; return v.f;
}
__device__ __forceinline__ ushort_t f2bf(float f){
  union{float f; unsigned u;} v; v.f=f;
  unsigned b = v.u + 0x7FFF + ((v.u>>16)&1);
  return (ushort_t)(b>>16);
}

__global__ void k_f32_to_bf16(const float* __restrict__ in, ushort_t* __restrict__ out, int n){
  int i = blockIdx.x*blockDim.x + threadIdx.x;
  int idx = i*4;
  if(idx+3<n){
    float4 v = *(const float4*)&in[idx];
    ushort2 a; a.x=f2bf(v.x); a.y=f2bf(v.y);
    ushort2 b; b.x=f2bf(v.z); b.y=f2bf(v.w);
    *(ushort2*)&out[idx] = a;
    *(ushort2*)&out[idx+2] = b;
  } else {
    for(int k=idx;k<n;k++) out[k]=f2bf(in[k]);
  }
}

// ---- CSR build: coarse radix partition by dst>>10, then per-bucket finalize ----

__global__ __launch_bounds__(512) void k_hist(const int* __restrict__ dst, int* __restrict__ bcnt, int n){
  __shared__ int lh[NBUCK];
  int t=threadIdx.x;
  if(t<NBUCK) lh[t]=0;
  __syncthreads();
  int base = blockIdx.x*EPB;
  #pragma unroll
  for(int j=0;j<8;j++){
    int e = base + t + j*512;
    if(e<n) atomicAdd(&lh[dst[e]>>10], 1);
  }
  __syncthreads();
  if(t<NBUCK && lh[t]) atomicAdd(&bcnt[t], lh[t]);
}

// gbase[t] = exclusive prefix (bucket edge base), gbase[NBUCK] = total;
// gcur[t] = running cursor for k_reorder.
__global__ void k_scan128(const int* __restrict__ bcnt, int* __restrict__ gcur, int* __restrict__ gbase){
  __shared__ int s[NBUCK];
  int t=threadIdx.x;
  int v=bcnt[t]; s[t]=v;
  __syncthreads();
  for(int off=1; off<NBUCK; off<<=1){
    int a=(t>=off)? s[t-off]:0;
    __syncthreads();
    s[t]+=a;
    __syncthreads();
  }
  int excl = s[t]-v;
  gcur[t]=excl;
  gbase[t]=excl;
  if(t==NBUCK-1) gbase[NBUCK]=s[t];
}

__global__ __launch_bounds__(512) void k_reorder(
    const int* __restrict__ src, const int* __restrict__ dst,
    int* __restrict__ gcur, int2* __restrict__ pairs, int n){
  __shared__ int lh[NBUCK];
  __shared__ int lbase[NBUCK];
  int t=threadIdx.x;
  if(t<NBUCK) lh[t]=0;
  __syncthreads();
  int base = blockIdx.x*EPB;
  int bb[8], rr[8], sv[8], dv[8];
  #pragma unroll
  for(int j=0;j<8;j++){
    int e = base + t + j*512;
    if(e<n){
      int d=dst[e];
      int b=d>>10;
      rr[j]=atomicAdd(&lh[b],1);
      bb[j]=b; sv[j]=src[e]; dv[j]=d;
    } else bb[j]=-1;
  }
  __syncthreads();
  if(t<NBUCK && lh[t]) lbase[t]=atomicAdd(&gcur[t], lh[t]);
  __syncthreads();
  #pragma unroll
  for(int j=0;j<8;j++){
    if(bb[j]>=0){
      int pos = lbase[bb[j]] + rr[j];
      pairs[pos] = make_int2(sv[j], dv[j]);
    }
  }
}

// One block per bucket: LDS hist over 1024 local nodes -> block scan ->
// rowptr/invdeg -> LDS-cursor scatter into the bucket's private csr window.
// All csr writes for the window come from ONE block (one XCD's L2).
__global__ __launch_bounds__(512) void k_bucket_csr(
    const int2* __restrict__ pairs, const int* __restrict__ gbase,
    int* __restrict__ rowptr, float* __restrict__ invdeg,
    int* __restrict__ csr, int nnodes, int nedges){
  __shared__ int cnt[BNODES];
  __shared__ int part[512];
  int t=threadIdx.x, b=blockIdx.x;
  int nb0 = b*BNODES;
  int e0 = gbase[b], e1 = gbase[b+1];
  cnt[t]=0; cnt[t+512]=0;
  __syncthreads();
  for(int e=e0+t; e<e1; e+=512) atomicAdd(&cnt[pairs[e].y - nb0], 1);
  __syncthreads();
  int c0 = cnt[2*t], c1 = cnt[2*t+1];
  part[t] = c0+c1;
  __syncthreads();
  for(int off=1; off<512; off<<=1){
    int a=(t>=off)? part[t-off]:0;
    __syncthreads();
    part[t]+=a;
    __syncthreads();
  }
  int base = part[t]-(c0+c1);
  int ex0 = base, ex1 = base+c0;
  int n_0 = nb0+2*t, n_1 = nb0+2*t+1;
  if(n_0<nnodes){ rowptr[n_0]=e0+ex0; invdeg[n_0]=1.0f/fmaxf((float)c0,1.0f); }
  if(n_1<nnodes){ rowptr[n_1]=e0+ex1; invdeg[n_1]=1.0f/fmaxf((float)c1,1.0f); }
  if(b==0 && t==0) rowptr[nnodes]=nedges;
  cnt[2*t]=ex0; cnt[2*t+1]=ex1;      // become cursors
  __syncthreads();
  for(int e=e0+t; e<e1; e+=512){
    int2 p = pairs[e];
    int pos = atomicAdd(&cnt[p.y - nb0], 1);
    csr[e0+pos] = p.x;
  }
}

// Pure gather: one wave per node. slot = lane>>3 (8 edge slots), c = lane&7
// (16B feature chunk). One VMEM instruction gathers 8 edges; 16 rows in
// flight per wave. agg[node] = mean of neighbor rows, bf16.
__global__ __launch_bounds__(512) void k_gather(
    const ushort_t* __restrict__ hin, ushort_t* __restrict__ agg,
    const int* __restrict__ rowptr, const int* __restrict__ csr,
    const float* __restrict__ invdeg, int nnodes)
{
  int t=threadIdx.x;
  int lane=t&63, wid=t>>6;
  int node=blockIdx.x*8+wid;
  if(node>=nnodes) return;
  int start=rowptr[node], end=rowptr[node+1];
  int slot = lane>>3;
  int c    = lane&7;
  float idg = invdeg[node];
  float acc[8]={0,0,0,0,0,0,0,0};
  for(int e=start; e<end; e+=16){
    int i1 = e + slot, i2 = e + 8 + slot;
    int c1 = i1<end ? i1 : end-1;
    int c2 = i2<end ? i2 : end-1;
    int s1 = csr[c1], s2 = csr[c2];
    ushort8_t v1 = *(const ushort8_t*)&hin[(size_t)s1*HD + c*8];
    ushort8_t v2 = *(const ushort8_t*)&hin[(size_t)s2*HD + c*8];
    float m1 = i1<end ? 1.f : 0.f;
    float m2 = i2<end ? 1.f : 0.f;
    #pragma unroll
    for(int j=0;j<8;j++){
      acc[j] = fmaf(m1, bf2f(v1[j]), acc[j]);
      acc[j] = fmaf(m2, bf2f(v2[j]), acc[j]);
    }
  }
  #pragma unroll
  for(int off=8; off<64; off<<=1){
    #pragma unroll
    for(int j=0;j<8;j++) acc[j] += __shfl_xor(acc[j], off, 64);
  }
  if(slot==0){
    ushort8_t o;
    #pragma unroll
    for(int j=0;j<8;j++) o[j] = f2bf(acc[j]*idg);
    *(ushort8_t*)&agg[(size_t)node*HD + c*8] = o;
  }
}

// Register-tiled dense: out = relu([agg|h] @ [Wl;Wr] + b), fused JK dot (+sigmoid).
__global__ __launch_bounds__(256) void k_dense(
    const ushort_t* __restrict__ hin, const ushort_t* __restrict__ agg,
    ushort_t* __restrict__ hout,
    const float* __restrict__ Wl, const float* __restrict__ bvec, const float* __restrict__ Wr,
    const float* __restrict__ wseg, const float* __restrict__ blin,
    float* __restrict__ partial, float* __restrict__ finout,
    int first, int nnodes)
{
  __shared__ ushort_t sA[TILE][134];
  __shared__ ushort_t sW[128][72];
  __shared__ float sB[64], sS[64];
  __shared__ float sJKp[8][TILE];
  int t = threadIdx.x;
  int n0 = blockIdx.x*TILE;

  {
    int nl = t>>1, half = t&1;
    int n = n0 + nl;
    const ushort_t* srcp = half ? hin : agg;
    #pragma unroll
    for(int j=0;j<8;j++){
      uint4 v = make_uint4(0u,0u,0u,0u);
      if(n < nnodes) v = *(const uint4*)&srcp[(size_t)n*HD + j*8];
      uint* dstp = (uint*)&sA[nl][half*64 + j*8];
      dstp[0]=v.x; dstp[1]=v.y; dstp[2]=v.z; dstp[3]=v.w;
    }
  }
  #pragma unroll
  for(int r=0;r<8;r++){
    int elem = r*1024 + t*4;
    int k = elem>>6, j = elem&63;
    const float* srcw = (k<64) ? &Wl[k*64+j] : &Wr[(k-64)*64+j];
    float4 w = *(const float4*)srcw;
    ushort4_t o; o[0]=f2bf(w.x); o[1]=f2bf(w.y); o[2]=f2bf(w.z); o[3]=f2bf(w.w);
    *(ushort4_t*)&sW[k][j] = o;
  }
  if(t<64){ sB[t]=bvec[t]; sS[t]=wseg[t]; }
  __syncthreads();

  int g = t>>5, nl = t&31;
  float acc[4][8];
  #pragma unroll
  for(int i=0;i<4;i++)
    #pragma unroll
    for(int j=0;j<8;j++) acc[i][j]=0.f;

  for(int k=0;k<128;k++){
    float a0 = bf2f(sA[nl   ][k]);
    float a1 = bf2f(sA[nl+32][k]);
    float a2 = bf2f(sA[nl+64][k]);
    float a3 = bf2f(sA[nl+96][k]);
    ushort8_t wv = *(const ushort8_t*)&sW[k][g*8];
    #pragma unroll
    for(int j=0;j<8;j++){
      float w = bf2f(wv[j]);
      acc[0][j] = fmaf(a0,w,acc[0][j]);
      acc[1][j] = fmaf(a1,w,acc[1][j]);
      acc[2][j] = fmaf(a2,w,acc[2][j]);
      acc[3][j] = fmaf(a3,w,acc[3][j]);
    }
  }

  #pragma unroll
  for(int i=0;i<4;i++){
    int nlc = nl + i*32;
    int n = n0 + nlc;
    float p = 0.f;
    ushort8_t o;
    #pragma unroll
    for(int j=0;j<8;j++){
      float r = fmaxf(acc[i][j] + sB[g*8+j], 0.f);
      p = fmaf(r, sS[g*8+j], p);
      o[j] = f2bf(r);
    }
    if(!finout && n<nnodes) *(ushort8_t*)&hout[(size_t)n*HD + g*8] = o;
    sJKp[g][nlc] = p;
  }
  __syncthreads();
  if(t < TILE){
    int n = n0 + t;
    if(n < nnodes){
      float ssum = 0.f;
      #pragma unroll
      for(int gg=0; gg<8; gg++) ssum += sJKp[gg][t];
      float p = first ? (blin[0] + ssum) : (partial[n] + ssum);
      if(finout) finout[n] = 1.0f/(1.0f+expf(-p));
      else partial[n] = p;
    }
  }
}

extern "C" void kernel_launch(void* const* d_in, const int* in_sizes, int n_in,
                              void* d_out, int out_size, void* d_ws, size_t ws_size,
                              hipStream_t stream){
  const float* x    =(const float*)d_in[0];
  const int*   ei   =(const int*)  d_in[1];
  const float* W1l  =(const float*)d_in[2];
  const float* b1   =(const float*)d_in[3];
  const float* W1r  =(const float*)d_in[4];
  const float* W2l  =(const float*)d_in[5];
  const float* b2   =(const float*)d_in[6];
  const float* W2r  =(const float*)d_in[7];
  const float* W3l  =(const float*)d_in[8];
  const float* b3   =(const float*)d_in[9];
  const float* W3r  =(const float*)d_in[10];
  const float* Wlin =(const float*)d_in[11];
  const float* blin =(const float*)d_in[12];
  float* out=(float*)d_out;

  const int N=N_NODES, E=N_EDGES;
  char* ws=(char*)d_ws;
  size_t off=0;
  auto take=[&](size_t bytes)->char*{ char* p=ws+off; off=(off+bytes+255)&~(size_t)255; return p; };
  int*      bcnt     =(int*)     take((size_t)NBUCK*4);
  int*      gcur     =(int*)     take((size_t)NBUCK*4);
  int*      gbase    =(int*)     take((size_t)(NBUCK+1)*4);
  int*      rowptr   =(int*)     take((size_t)(N+1)*4);
  int*      csr      =(int*)     take((size_t)E*4);
  int2*     pairs    =(int2*)    take((size_t)E*8);
  float*    invdeg   =(float*)   take((size_t)N*4);
  ushort_t* xbf      =(ushort_t*)take((size_t)N*HD*2);
  ushort_t* hbfA     =(ushort_t*)take((size_t)N*HD*2);
  ushort_t* hbfB     =(ushort_t*)take((size_t)N*HD*2);
  ushort_t* aggbf    =(ushort_t*)take((size_t)N*HD*2);
  float*    pacc     =(float*)   take((size_t)N*4);

  const int RB=(E+EPB-1)/EPB;           // 391 (hist/reorder)
  const int CB=(N*HD/4+255)/256;        // bf16 convert blocks
  const int BB=(N+BNODES-1)/BNODES;     // 98 buckets

  hipMemsetAsync(bcnt, 0, (size_t)NBUCK*4, stream);
  k_f32_to_bf16<<<CB, 256, 0, stream>>>(x, xbf, N*HD);
  k_hist       <<<RB, 512, 0, stream>>>(ei+E, bcnt, E);
  k_scan128    <<<1, NBUCK, 0, stream>>>(bcnt, gcur, gbase);
  k_reorder    <<<RB, 512, 0, stream>>>(ei, ei+E, gcur, pairs, E);
  k_bucket_csr <<<BB, 512, 0, stream>>>(pairs, gbase, rowptr, invdeg, csr, N, E);

  dim3 gg((N+7)/8);
  dim3 gd((N+TILE-1)/TILE);

  k_gather<<<gg, 512, 0, stream>>>(xbf, aggbf, rowptr, csr, invdeg, N);
  k_dense <<<gd, 256, 0, stream>>>(xbf, aggbf, hbfA, W1l,b1,W1r, Wlin+0,  blin, pacc, (float*)nullptr, 1, N);
  k_gather<<<gg, 512, 0, stream>>>(hbfA, aggbf, rowptr, csr, invdeg, N);
  k_dense <<<gd, 256, 0, stream>>>(hbfA, aggbf, hbfB, W2l,b2,W2r, Wlin+64, blin, pacc, (float*)nullptr, 0, N);
  k_gather<<<gg, 512, 0, stream>>>(hbfB, aggbf, rowptr, csr, invdeg, N);
  k_dense <<<gd, 256, 0, stream>>>(hbfB, aggbf, hbfA, W3l,b3,W3r, Wlin+128, blin, pacc, out, 0, N);
}

// Round 13
// 220.280 us; speedup vs baseline: 5.8398x; 1.3833x over previous
//
#include <hip/hip_runtime.h>
#include <math.h>

#define N_NODES 100000
#define N_EDGES 1600000
#define HD 64
#define TILE 128
#define NBUCK 128          // dst>>10 -> 98 used buckets
#define BNODES 1024
#define EPB 4096           // edges per block in hist/reorder

typedef unsigned short ushort_t;
typedef __attribute__((ext_vector_type(8))) unsigned short ushort8_t;
typedef __attribute__((ext_vector_type(8))) short short8_t;
typedef __attribute__((ext_vector_type(4))) float float4_t;

__device__ __forceinline__ float bf2f(ushort_t h){
  union{unsigned u; float f;} v; v.u = ((unsigned)h)<<16; return v.f;
}
__device__ __forceinline__ ushort_t f2bf(float f){
  union{float f; unsigned u;} v; v.f=f;
  unsigned b = v.u + 0x7FFF + ((v.u>>16)&1);
  return (ushort_t)(b>>16);
}

__global__ void k_f32_to_bf16(const float* __restrict__ in, ushort_t* __restrict__ out, int n){
  int i = blockIdx.x*blockDim.x + threadIdx.x;
  int idx = i*4;
  if(idx+3<n){
    float4 v = *(const float4*)&in[idx];
    ushort2 a; a.x=f2bf(v.x); a.y=f2bf(v.y);
    ushort2 b; b.x=f2bf(v.z); b.y=f2bf(v.w);
    *(ushort2*)&out[idx] = a;
    *(ushort2*)&out[idx+2] = b;
  } else {
    for(int k=idx;k<n;k++) out[k]=f2bf(in[k]);
  }
}

// ---- CSR build: coarse radix partition by dst>>10, then per-bucket finalize ----

__global__ __launch_bounds__(512) void k_hist(const int* __restrict__ dst, int* __restrict__ bcnt, int n){
  __shared__ int lh[NBUCK];
  int t=threadIdx.x;
  if(t<NBUCK) lh[t]=0;
  __syncthreads();
  int base = blockIdx.x*EPB;
  #pragma unroll
  for(int j=0;j<8;j++){
    int e = base + t + j*512;
    if(e<n) atomicAdd(&lh[dst[e]>>10], 1);
  }
  __syncthreads();
  if(t<NBUCK && lh[t]) atomicAdd(&bcnt[t], lh[t]);
}

// gbase[t] = exclusive prefix (bucket edge base), gbase[NBUCK] = total;
// gcur[t] = running cursor for k_reorder.
__global__ void k_scan128(const int* __restrict__ bcnt, int* __restrict__ gcur, int* __restrict__ gbase){
  __shared__ int s[NBUCK];
  int t=threadIdx.x;
  int v=bcnt[t]; s[t]=v;
  __syncthreads();
  for(int off=1; off<NBUCK; off<<=1){
    int a=(t>=off)? s[t-off]:0;
    __syncthreads();
    s[t]+=a;
    __syncthreads();
  }
  int excl = s[t]-v;
  gcur[t]=excl;
  gbase[t]=excl;
  if(t==NBUCK-1) gbase[NBUCK]=s[t];
}

__global__ __launch_bounds__(512) void k_reorder(
    const int* __restrict__ src, const int* __restrict__ dst,
    int* __restrict__ gcur, int2* __restrict__ pairs, int n){
  __shared__ int lh[NBUCK];
  __shared__ int lbase[NBUCK];
  int t=threadIdx.x;
  if(t<NBUCK) lh[t]=0;
  __syncthreads();
  int base = blockIdx.x*EPB;
  int bb[8], rr[8], sv[8], dv[8];
  #pragma unroll
  for(int j=0;j<8;j++){
    int e = base + t + j*512;
    if(e<n){
      int d=dst[e];
      int b=d>>10;
      rr[j]=atomicAdd(&lh[b],1);
      bb[j]=b; sv[j]=src[e]; dv[j]=d;
    } else bb[j]=-1;
  }
  __syncthreads();
  if(t<NBUCK && lh[t]) lbase[t]=atomicAdd(&gcur[t], lh[t]);
  __syncthreads();
  #pragma unroll
  for(int j=0;j<8;j++){
    if(bb[j]>=0){
      int pos = lbase[bb[j]] + rr[j];
      pairs[pos] = make_int2(sv[j], dv[j]);
    }
  }
}

// One block per bucket: LDS hist over 1024 local nodes -> block scan ->
// rowptr/invdeg -> LDS-cursor scatter into the bucket's private csr window.
__global__ __launch_bounds__(512) void k_bucket_csr(
    const int2* __restrict__ pairs, const int* __restrict__ gbase,
    int* __restrict__ rowptr, float* __restrict__ invdeg,
    int* __restrict__ csr, int nnodes, int nedges){
  __shared__ int cnt[BNODES];
  __shared__ int part[512];
  int t=threadIdx.x, b=blockIdx.x;
  int nb0 = b*BNODES;
  int e0 = gbase[b], e1 = gbase[b+1];
  cnt[t]=0; cnt[t+512]=0;
  __syncthreads();
  for(int e=e0+t; e<e1; e+=512) atomicAdd(&cnt[pairs[e].y - nb0], 1);
  __syncthreads();
  int c0 = cnt[2*t], c1 = cnt[2*t+1];
  part[t] = c0+c1;
  __syncthreads();
  for(int off=1; off<512; off<<=1){
    int a=(t>=off)? part[t-off]:0;
    __syncthreads();
    part[t]+=a;
    __syncthreads();
  }
  int base = part[t]-(c0+c1);
  int ex0 = base, ex1 = base+c0;
  int n_0 = nb0+2*t, n_1 = nb0+2*t+1;
  if(n_0<nnodes){ rowptr[n_0]=e0+ex0; invdeg[n_0]=1.0f/fmaxf((float)c0,1.0f); }
  if(n_1<nnodes){ rowptr[n_1]=e0+ex1; invdeg[n_1]=1.0f/fmaxf((float)c1,1.0f); }
  if(b==0 && t==0) rowptr[nnodes]=nedges;
  cnt[2*t]=ex0; cnt[2*t+1]=ex1;      // become cursors
  __syncthreads();
  for(int e=e0+t; e<e1; e+=512){
    int2 p = pairs[e];
    int pos = atomicAdd(&cnt[p.y - nb0], 1);
    csr[e0+pos] = p.x;
  }
}

// Pure gather: one wave per node. slot = lane>>3 (8 edge slots), c = lane&7
// (16B feature chunk). agg[node] = mean of neighbor rows, bf16.
__global__ __launch_bounds__(512) void k_gather(
    const ushort_t* __restrict__ hin, ushort_t* __restrict__ agg,
    const int* __restrict__ rowptr, const int* __restrict__ csr,
    const float* __restrict__ invdeg, int nnodes)
{
  int t=threadIdx.x;
  int lane=t&63, wid=t>>6;
  int node=blockIdx.x*8+wid;
  if(node>=nnodes) return;
  int start=rowptr[node], end=rowptr[node+1];
  int slot = lane>>3;
  int c    = lane&7;
  float idg = invdeg[node];
  float acc[8]={0,0,0,0,0,0,0,0};
  for(int e=start; e<end; e+=16){
    int i1 = e + slot, i2 = e + 8 + slot;
    int c1 = i1<end ? i1 : end-1;
    int c2 = i2<end ? i2 : end-1;
    int s1 = csr[c1], s2 = csr[c2];
    ushort8_t v1 = *(const ushort8_t*)&hin[(size_t)s1*HD + c*8];
    ushort8_t v2 = *(const ushort8_t*)&hin[(size_t)s2*HD + c*8];
    float m1 = i1<end ? 1.f : 0.f;
    float m2 = i2<end ? 1.f : 0.f;
    #pragma unroll
    for(int j=0;j<8;j++){
      acc[j] = fmaf(m1, bf2f(v1[j]), acc[j]);
      acc[j] = fmaf(m2, bf2f(v2[j]), acc[j]);
    }
  }
  #pragma unroll
  for(int off=8; off<64; off<<=1){
    #pragma unroll
    for(int j=0;j<8;j++) acc[j] += __shfl_xor(acc[j], off, 64);
  }
  if(slot==0){
    ushort8_t o;
    #pragma unroll
    for(int j=0;j<8;j++) o[j] = f2bf(acc[j]*idg);
    *(ushort8_t*)&agg[(size_t)node*HD + c*8] = o;
  }
}

// MFMA dense: C[N,64] = relu([agg|h] @ [Wl;Wr] + b), fused JK dot (+sigmoid).
// Block 256 = 4 waves; 128 nodes/block; wave: 32 nodes x 64 cols = 32 MFMA
// (16x16x32 bf16). A-frags from global (row-major); B-frags from W^T in LDS.
// C/D layout: col=lane&15, row=(lane>>4)*4+reg (m89-verified).
__global__ __launch_bounds__(256) void k_dense(
    const ushort_t* __restrict__ hin, const ushort_t* __restrict__ agg,
    ushort_t* __restrict__ hout,
    const float* __restrict__ Wl, const float* __restrict__ bvec, const float* __restrict__ Wr,
    const float* __restrict__ wseg, const float* __restrict__ blin,
    float* __restrict__ partial, float* __restrict__ finout,
    int first, int nnodes)
{
  __shared__ ushort_t sWt[64][136];   // W^T bf16: [col][k]; 272B stride -> 2-way (free)
  __shared__ ushort_t sOut[TILE][72]; // relu'd outputs bf16, 16B-aligned rows
  __shared__ float sB[64], sS[64];
  int t = threadIdx.x;
  int n0 = blockIdx.x*TILE;

  // stage W^T (f32 global, coalesced by col) -> bf16 LDS
  {
    int col = t & 63;
    int k0  = (t >> 6) * 32;
    #pragma unroll
    for (int j = 0; j < 32; ++j) {
      int k = k0 + j;
      float wv = (k < 64) ? Wl[k*64 + col] : Wr[(k-64)*64 + col];
      sWt[col][k] = f2bf(wv);
    }
  }
  if(t<64){ sB[t]=bvec[t]; sS[t]=wseg[t]; }
  __syncthreads();

  int lane = t & 63, wv_ = t >> 6;
  int r16 = lane & 15, g4 = lane >> 4;
  int nbase = n0 + wv_*32;

  float4_t acc[2][4];
  #pragma unroll
  for(int mt=0;mt<2;mt++)
    #pragma unroll
    for(int ct=0;ct<4;ct++)
      #pragma unroll
      for(int r=0;r<4;r++) acc[mt][ct][r]=0.f;

  #pragma unroll
  for (int ks = 0; ks < 4; ++ks) {
    const ushort_t* abuf = (ks < 2) ? agg : hin;   // k<64: agg, k>=64: h
    int koff = (ks & 1)*32 + g4*8;
    short8_t aF[2];
    #pragma unroll
    for (int mt = 0; mt < 2; ++mt) {
      int node = nbase + mt*16 + r16;
      if (node >= nnodes) node = nnodes-1;         // clamp; stores guarded
      aF[mt] = *(const short8_t*)&abuf[(size_t)node*HD + koff];
    }
    #pragma unroll
    for (int ct = 0; ct < 4; ++ct) {
      short8_t bF = *(const short8_t*)&sWt[ct*16 + r16][ks*32 + g4*8];
      acc[0][ct] = __builtin_amdgcn_mfma_f32_16x16x32_bf16(aF[0], bF, acc[0][ct], 0,0,0);
      acc[1][ct] = __builtin_amdgcn_mfma_f32_16x16x32_bf16(aF[1], bF, acc[1][ct], 0,0,0);
    }
  }

  // epilogue: bias + relu -> bf16 LDS
  #pragma unroll
  for (int mt = 0; mt < 2; ++mt)
    #pragma unroll
    for (int ct = 0; ct < 4; ++ct) {
      int col = ct*16 + r16;
      #pragma unroll
      for (int r = 0; r < 4; ++r) {
        int row = g4*4 + r;
        float v = fmaxf(acc[mt][ct][r] + sB[col], 0.f);
        sOut[wv_*32 + mt*16 + row][col] = f2bf(v);
      }
    }
  __syncthreads();

  // pass 2: vectorized global store + JK dot + partial/sigmoid
  {
    int nl = t >> 1, half = t & 1;
    int node = n0 + nl;
    float p = 0.f;
    #pragma unroll
    for (int i = 0; i < 4; ++i) {
      int c0 = half*32 + i*8;
      ushort8_t v = *(const ushort8_t*)&sOut[nl][c0];
      if (!finout && node < nnodes)
        *(ushort8_t*)&hout[(size_t)node*HD + c0] = v;
      #pragma unroll
      for (int j = 0; j < 8; ++j) p = fmaf(bf2f(v[j]), sS[c0+j], p);
    }
    p += __shfl_xor(p, 1, 64);
    if (half == 0 && node < nnodes) {
      float q = first ? (blin[0] + p) : (partial[node] + p);
      if (finout) finout[node] = 1.0f/(1.0f+expf(-q));
      else partial[node] = q;
    }
  }
}

extern "C" void kernel_launch(void* const* d_in, const int* in_sizes, int n_in,
                              void* d_out, int out_size, void* d_ws, size_t ws_size,
                              hipStream_t stream){
  const float* x    =(const float*)d_in[0];
  const int*   ei   =(const int*)  d_in[1];
  const float* W1l  =(const float*)d_in[2];
  const float* b1   =(const float*)d_in[3];
  const float* W1r  =(const float*)d_in[4];
  const float* W2l  =(const float*)d_in[5];
  const float* b2   =(const float*)d_in[6];
  const float* W2r  =(const float*)d_in[7];
  const float* W3l  =(const float*)d_in[8];
  const float* b3   =(const float*)d_in[9];
  const float* W3r  =(const float*)d_in[10];
  const float* Wlin =(const float*)d_in[11];
  const float* blin =(const float*)d_in[12];
  float* out=(float*)d_out;

  const int N=N_NODES, E=N_EDGES;
  char* ws=(char*)d_ws;
  size_t off=0;
  auto take=[&](size_t bytes)->char*{ char* p=ws+off; off=(off+bytes+255)&~(size_t)255; return p; };
  int*      bcnt     =(int*)     take((size_t)NBUCK*4);
  int*      gcur     =(int*)     take((size_t)NBUCK*4);
  int*      gbase    =(int*)     take((size_t)(NBUCK+1)*4);
  int*      rowptr   =(int*)     take((size_t)(N+1)*4);
  int*      csr      =(int*)     take((size_t)E*4);
  int2*     pairs    =(int2*)    take((size_t)E*8);
  float*    invdeg   =(float*)   take((size_t)N*4);
  ushort_t* xbf      =(ushort_t*)take((size_t)N*HD*2);
  ushort_t* hbfA     =(ushort_t*)take((size_t)N*HD*2);
  ushort_t* hbfB     =(ushort_t*)take((size_t)N*HD*2);
  ushort_t* aggbf    =(ushort_t*)take((size_t)N*HD*2);
  float*    pacc     =(float*)   take((size_t)N*4);

  const int RB=(E+EPB-1)/EPB;           // 391 (hist/reorder)
  const int CB=(N*HD/4+255)/256;        // bf16 convert blocks
  const int BB=(N+BNODES-1)/BNODES;     // 98 buckets

  hipMemsetAsync(bcnt, 0, (size_t)NBUCK*4, stream);
  k_f32_to_bf16<<<CB, 256, 0, stream>>>(x, xbf, N*HD);
  k_hist       <<<RB, 512, 0, stream>>>(ei+E, bcnt, E);
  k_scan128    <<<1, NBUCK, 0, stream>>>(bcnt, gcur, gbase);
  k_reorder    <<<RB, 512, 0, stream>>>(ei, ei+E, gcur, pairs, E);
  k_bucket_csr <<<BB, 512, 0, stream>>>(pairs, gbase, rowptr, invdeg, csr, N, E);

  dim3 gg((N+7)/8);
  dim3 gd((N+TILE-1)/TILE);

  k_gather<<<gg, 512, 0, stream>>>(xbf, aggbf, rowptr, csr, invdeg, N);
  k_dense <<<gd, 256, 0, stream>>>(xbf, aggbf, hbfA, W1l,b1,W1r, Wlin+0,  blin, pacc, (float*)nullptr, 1, N);
  k_gather<<<gg, 512, 0, stream>>>(hbfA, aggbf, rowptr, csr, invdeg, N);
  k_dense <<<gd, 256, 0, stream>>>(hbfA, aggbf, hbfB, W2l,b2,W2r, Wlin+64, blin, pacc, (float*)nullptr, 0, N);
  k_gather<<<gg, 512, 0, stream>>>(hbfB, aggbf, rowptr, csr, invdeg, N);
  k_dense <<<gd, 256, 0, stream>>>(hbfB, aggbf, hbfA, W3l,b3,W3r, Wlin+128, blin, pacc, out, 0, N);
}

// Round 14
// 217.759 us; speedup vs baseline: 5.9074x; 1.0116x over previous
//
#include <hip/hip_runtime.h>
#include <math.h>

#define N_NODES 100000
#define N_EDGES 1600000
#define HD 64
#define TILE 128
#define NBUCK 128          // dst>>10 -> 98 used buckets
#define BNODES 1024
#define EPB 4096           // edges per block in hist/reorder

typedef unsigned short ushort_t;
typedef unsigned char uchar_t;
typedef __attribute__((ext_vector_type(8))) unsigned short ushort8_t;
typedef __attribute__((ext_vector_type(8))) short short8_t;
typedef __attribute__((ext_vector_type(4))) float float4_t;
typedef __attribute__((ext_vector_type(2))) float float2_t;

__device__ __forceinline__ float bf2f(ushort_t h){
  union{unsigned u; float f;} v; v.u = ((unsigned)h)<<16; return v.f;
}
__device__ __forceinline__ ushort_t f2bf(float f){
  union{float f; unsigned u;} v; v.f=f;
  unsigned b = v.u + 0x7FFF + ((v.u>>16)&1);
  return (ushort_t)(b>>16);
}

// fused convert: x f32 -> bf16 copy + fp8(e4m3) copy
__global__ void k_convert_x(const float* __restrict__ in, ushort_t* __restrict__ obf,
                            uchar_t* __restrict__ o8, int n){
  int i = blockIdx.x*blockDim.x + threadIdx.x;
  int idx = i*4;
  if(idx+3<n){
    float4 v = *(const float4*)&in[idx];
    ushort2 a; a.x=f2bf(v.x); a.y=f2bf(v.y);
    ushort2 b; b.x=f2bf(v.z); b.y=f2bf(v.w);
    *(ushort2*)&obf[idx] = a;
    *(ushort2*)&obf[idx+2] = b;
    int p = __builtin_amdgcn_cvt_pk_fp8_f32(v.x, v.y, 0, false);
    p     = __builtin_amdgcn_cvt_pk_fp8_f32(v.z, v.w, p, true);
    *(unsigned int*)&o8[idx] = (unsigned int)p;
  } else {
    for(int k=idx;k<n;k++){
      obf[k]=f2bf(in[k]);
      int p = __builtin_amdgcn_cvt_pk_fp8_f32(in[k], 0.f, 0, false);
      o8[k] = (uchar_t)(p & 0xFF);
    }
  }
}

// ---- CSR build: coarse radix partition by dst>>10, then per-bucket finalize ----

__global__ __launch_bounds__(512) void k_hist(const int* __restrict__ dst, int* __restrict__ bcnt, int n){
  __shared__ int lh[NBUCK];
  int t=threadIdx.x;
  if(t<NBUCK) lh[t]=0;
  __syncthreads();
  int base = blockIdx.x*EPB;
  #pragma unroll
  for(int j=0;j<8;j++){
    int e = base + t + j*512;
    if(e<n) atomicAdd(&lh[dst[e]>>10], 1);
  }
  __syncthreads();
  if(t<NBUCK && lh[t]) atomicAdd(&bcnt[t], lh[t]);
}

__global__ void k_scan128(const int* __restrict__ bcnt, int* __restrict__ gcur, int* __restrict__ gbase){
  __shared__ int s[NBUCK];
  int t=threadIdx.x;
  int v=bcnt[t]; s[t]=v;
  __syncthreads();
  for(int off=1; off<NBUCK; off<<=1){
    int a=(t>=off)? s[t-off]:0;
    __syncthreads();
    s[t]+=a;
    __syncthreads();
  }
  int excl = s[t]-v;
  gcur[t]=excl;
  gbase[t]=excl;
  if(t==NBUCK-1) gbase[NBUCK]=s[t];
}

// packed pair: src (17b) | dstlocal<<17 (10b)
__global__ __launch_bounds__(512) void k_reorder(
    const int* __restrict__ src, const int* __restrict__ dst,
    int* __restrict__ gcur, int* __restrict__ pairs, int n){
  __shared__ int lh[NBUCK];
  __shared__ int lbase[NBUCK];
  int t=threadIdx.x;
  if(t<NBUCK) lh[t]=0;
  __syncthreads();
  int base = blockIdx.x*EPB;
  int bb[8], rr[8], pv[8];
  #pragma unroll
  for(int j=0;j<8;j++){
    int e = base + t + j*512;
    if(e<n){
      int d=dst[e];
      int b=d>>10;
      rr[j]=atomicAdd(&lh[b],1);
      bb[j]=b;
      pv[j]=src[e] | ((d & 1023)<<17);
    } else bb[j]=-1;
  }
  __syncthreads();
  if(t<NBUCK && lh[t]) lbase[t]=atomicAdd(&gcur[t], lh[t]);
  __syncthreads();
  #pragma unroll
  for(int j=0;j<8;j++){
    if(bb[j]>=0){
      int pos = lbase[bb[j]] + rr[j];
      pairs[pos] = pv[j];
    }
  }
}

// One block per bucket: LDS hist over 1024 local nodes -> scan -> rowptr/invdeg
// -> LDS-cursor scatter into the bucket's private csr window (one XCD's L2).
__global__ __launch_bounds__(512) void k_bucket_csr(
    const int* __restrict__ pairs, const int* __restrict__ gbase,
    int* __restrict__ rowptr, float* __restrict__ invdeg,
    int* __restrict__ csr, int nnodes, int nedges){
  __shared__ int cnt[BNODES];
  __shared__ int part[512];
  int t=threadIdx.x, b=blockIdx.x;
  int nb0 = b*BNODES;
  int e0 = gbase[b], e1 = gbase[b+1];
  cnt[t]=0; cnt[t+512]=0;
  __syncthreads();
  for(int e=e0+t; e<e1; e+=512) atomicAdd(&cnt[pairs[e]>>17], 1);
  __syncthreads();
  int c0 = cnt[2*t], c1 = cnt[2*t+1];
  part[t] = c0+c1;
  __syncthreads();
  for(int off=1; off<512; off<<=1){
    int a=(t>=off)? part[t-off]:0;
    __syncthreads();
    part[t]+=a;
    __syncthreads();
  }
  int base = part[t]-(c0+c1);
  int ex0 = base, ex1 = base+c0;
  int n_0 = nb0+2*t, n_1 = nb0+2*t+1;
  if(n_0<nnodes){ rowptr[n_0]=e0+ex0; invdeg[n_0]=1.0f/fmaxf((float)c0,1.0f); }
  if(n_1<nnodes){ rowptr[n_1]=e0+ex1; invdeg[n_1]=1.0f/fmaxf((float)c1,1.0f); }
  if(b==0 && t==0) rowptr[nnodes]=nedges;
  cnt[2*t]=ex0; cnt[2*t+1]=ex1;      // become cursors
  __syncthreads();
  for(int e=e0+t; e<e1; e+=512){
    int p = pairs[e];
    int pos = atomicAdd(&cnt[p>>17], 1);
    csr[e0+pos] = p & 0x1FFFF;
  }
}

// fp8 gather: one wave per node. slot = lane>>3 (8 edge slots), c = lane&7
// (8B feature chunk = 8 fp8). One VMEM instr gathers 8 rows (64B lines).
// agg[node] = mean of neighbor rows -> bf16.
__global__ __launch_bounds__(512) void k_gather(
    const uchar_t* __restrict__ hin8, ushort_t* __restrict__ agg,
    const int* __restrict__ rowptr, const int* __restrict__ csr,
    const float* __restrict__ invdeg, int nnodes)
{
  int t=threadIdx.x;
  int lane=t&63, wid=t>>6;
  int node=blockIdx.x*8+wid;
  if(node>=nnodes) return;
  int start=rowptr[node], end=rowptr[node+1];
  int slot = lane>>3;
  int c    = lane&7;
  float idg = invdeg[node];
  float acc[8]={0,0,0,0,0,0,0,0};
  for(int e=start; e<end; e+=16){
    int i1 = e + slot, i2 = e + 8 + slot;
    int c1 = i1<end ? i1 : end-1;
    int c2 = i2<end ? i2 : end-1;
    int s1 = csr[c1], s2 = csr[c2];
    uint2 u1 = *(const uint2*)&hin8[(size_t)s1*HD + c*8];
    uint2 u2 = *(const uint2*)&hin8[(size_t)s2*HD + c*8];
    float m1 = i1<end ? 1.f : 0.f;
    float m2 = i2<end ? 1.f : 0.f;
    float2_t f;
    f = __builtin_amdgcn_cvt_pk_f32_fp8((int)u1.x, false); acc[0]=fmaf(m1,f.x,acc[0]); acc[1]=fmaf(m1,f.y,acc[1]);
    f = __builtin_amdgcn_cvt_pk_f32_fp8((int)u1.x, true ); acc[2]=fmaf(m1,f.x,acc[2]); acc[3]=fmaf(m1,f.y,acc[3]);
    f = __builtin_amdgcn_cvt_pk_f32_fp8((int)u1.y, false); acc[4]=fmaf(m1,f.x,acc[4]); acc[5]=fmaf(m1,f.y,acc[5]);
    f = __builtin_amdgcn_cvt_pk_f32_fp8((int)u1.y, true ); acc[6]=fmaf(m1,f.x,acc[6]); acc[7]=fmaf(m1,f.y,acc[7]);
    f = __builtin_amdgcn_cvt_pk_f32_fp8((int)u2.x, false); acc[0]=fmaf(m2,f.x,acc[0]); acc[1]=fmaf(m2,f.y,acc[1]);
    f = __builtin_amdgcn_cvt_pk_f32_fp8((int)u2.x, true ); acc[2]=fmaf(m2,f.x,acc[2]); acc[3]=fmaf(m2,f.y,acc[3]);
    f = __builtin_amdgcn_cvt_pk_f32_fp8((int)u2.y, false); acc[4]=fmaf(m2,f.x,acc[4]); acc[5]=fmaf(m2,f.y,acc[5]);
    f = __builtin_amdgcn_cvt_pk_f32_fp8((int)u2.y, true ); acc[6]=fmaf(m2,f.x,acc[6]); acc[7]=fmaf(m2,f.y,acc[7]);
  }
  #pragma unroll
  for(int off=8; off<64; off<<=1){
    #pragma unroll
    for(int j=0;j<8;j++) acc[j] += __shfl_xor(acc[j], off, 64);
  }
  if(slot==0){
    ushort8_t o;
    #pragma unroll
    for(int j=0;j<8;j++) o[j] = f2bf(acc[j]*idg);
    *(ushort8_t*)&agg[(size_t)node*HD + c*8] = o;
  }
}

// MFMA dense: C[N,64] = relu([agg|h] @ [Wl;Wr] + b), fused JK dot (+sigmoid).
// Epilogue also emits the fp8 copy of h for the next layer's gather.
__global__ __launch_bounds__(256) void k_dense(
    const ushort_t* __restrict__ hin, const ushort_t* __restrict__ agg,
    ushort_t* __restrict__ hout, uchar_t* __restrict__ h8out,
    const float* __restrict__ Wl, const float* __restrict__ bvec, const float* __restrict__ Wr,
    const float* __restrict__ wseg, const float* __restrict__ blin,
    float* __restrict__ partial, float* __restrict__ finout,
    int first, int nnodes)
{
  __shared__ ushort_t sWt[64][136];   // W^T bf16: [col][k]; 272B stride -> 2-way (free)
  __shared__ ushort_t sOut[TILE][72]; // relu'd outputs bf16
  __shared__ float sB[64], sS[64];
  int t = threadIdx.x;
  int n0 = blockIdx.x*TILE;

  {
    int col = t & 63;
    int k0  = (t >> 6) * 32;
    #pragma unroll
    for (int j = 0; j < 32; ++j) {
      int k = k0 + j;
      float wv = (k < 64) ? Wl[k*64 + col] : Wr[(k-64)*64 + col];
      sWt[col][k] = f2bf(wv);
    }
  }
  if(t<64){ sB[t]=bvec[t]; sS[t]=wseg[t]; }
  __syncthreads();

  int lane = t & 63, wv_ = t >> 6;
  int r16 = lane & 15, g4 = lane >> 4;
  int nbase = n0 + wv_*32;

  float4_t acc[2][4];
  #pragma unroll
  for(int mt=0;mt<2;mt++)
    #pragma unroll
    for(int ct=0;ct<4;ct++)
      #pragma unroll
      for(int r=0;r<4;r++) acc[mt][ct][r]=0.f;

  #pragma unroll
  for (int ks = 0; ks < 4; ++ks) {
    const ushort_t* abuf = (ks < 2) ? agg : hin;   // k<64: agg, k>=64: h
    int koff = (ks & 1)*32 + g4*8;
    short8_t aF[2];
    #pragma unroll
    for (int mt = 0; mt < 2; ++mt) {
      int node = nbase + mt*16 + r16;
      if (node >= nnodes) node = nnodes-1;         // clamp; stores guarded
      aF[mt] = *(const short8_t*)&abuf[(size_t)node*HD + koff];
    }
    #pragma unroll
    for (int ct = 0; ct < 4; ++ct) {
      short8_t bF = *(const short8_t*)&sWt[ct*16 + r16][ks*32 + g4*8];
      acc[0][ct] = __builtin_amdgcn_mfma_f32_16x16x32_bf16(aF[0], bF, acc[0][ct], 0,0,0);
      acc[1][ct] = __builtin_amdgcn_mfma_f32_16x16x32_bf16(aF[1], bF, acc[1][ct], 0,0,0);
    }
  }

  #pragma unroll
  for (int mt = 0; mt < 2; ++mt)
    #pragma unroll
    for (int ct = 0; ct < 4; ++ct) {
      int col = ct*16 + r16;
      #pragma unroll
      for (int r = 0; r < 4; ++r) {
        int row = g4*4 + r;
        float v = fmaxf(acc[mt][ct][r] + sB[col], 0.f);
        sOut[wv_*32 + mt*16 + row][col] = f2bf(v);
      }
    }
  __syncthreads();

  // pass 2: vectorized stores (bf16 + fp8) + JK dot + partial/sigmoid
  {
    int nl = t >> 1, half = t & 1;
    int node = n0 + nl;
    float p = 0.f;
    #pragma unroll
    for (int i = 0; i < 4; ++i) {
      int c0 = half*32 + i*8;
      ushort8_t v = *(const ushort8_t*)&sOut[nl][c0];
      float fv[8];
      #pragma unroll
      for (int j = 0; j < 8; ++j){ fv[j]=bf2f(v[j]); p = fmaf(fv[j], sS[c0+j], p); }
      if (!finout && node < nnodes){
        *(ushort8_t*)&hout[(size_t)node*HD + c0] = v;
        int q0 = __builtin_amdgcn_cvt_pk_fp8_f32(fv[0], fv[1], 0, false);
        q0     = __builtin_amdgcn_cvt_pk_fp8_f32(fv[2], fv[3], q0, true);
        int q1 = __builtin_amdgcn_cvt_pk_fp8_f32(fv[4], fv[5], 0, false);
        q1     = __builtin_amdgcn_cvt_pk_fp8_f32(fv[6], fv[7], q1, true);
        uint2 st; st.x=(unsigned)q0; st.y=(unsigned)q1;
        *(uint2*)&h8out[(size_t)node*HD + c0] = st;
      }
    }
    p += __shfl_xor(p, 1, 64);
    if (half == 0 && node < nnodes) {
      float q = first ? (blin[0] + p) : (partial[node] + p);
      if (finout) finout[node] = 1.0f/(1.0f+expf(-q));
      else partial[node] = q;
    }
  }
}

extern "C" void kernel_launch(void* const* d_in, const int* in_sizes, int n_in,
                              void* d_out, int out_size, void* d_ws, size_t ws_size,
                              hipStream_t stream){
  const float* x    =(const float*)d_in[0];
  const int*   ei   =(const int*)  d_in[1];
  const float* W1l  =(const float*)d_in[2];
  const float* b1   =(const float*)d_in[3];
  const float* W1r  =(const float*)d_in[4];
  const float* W2l  =(const float*)d_in[5];
  const float* b2   =(const float*)d_in[6];
  const float* W2r  =(const float*)d_in[7];
  const float* W3l  =(const float*)d_in[8];
  const float* b3   =(const float*)d_in[9];
  const float* W3r  =(const float*)d_in[10];
  const float* Wlin =(const float*)d_in[11];
  const float* blin =(const float*)d_in[12];
  float* out=(float*)d_out;

  const int N=N_NODES, E=N_EDGES;
  char* ws=(char*)d_ws;
  size_t off=0;
  auto take=[&](size_t bytes)->char*{ char* p=ws+off; off=(off+bytes+255)&~(size_t)255; return p; };
  int*      bcnt     =(int*)     take((size_t)NBUCK*4);
  int*      gcur     =(int*)     take((size_t)NBUCK*4);
  int*      gbase    =(int*)     take((size_t)(NBUCK+1)*4);
  int*      rowptr   =(int*)     take((size_t)(N+1)*4);
  int*      csr      =(int*)     take((size_t)E*4);
  int*      pairs    =(int*)     take((size_t)E*4);
  float*    invdeg   =(float*)   take((size_t)N*4);
  ushort_t* xbf      =(ushort_t*)take((size_t)N*HD*2);
  ushort_t* hbfA     =(ushort_t*)take((size_t)N*HD*2);
  ushort_t* hbfB     =(ushort_t*)take((size_t)N*HD*2);
  ushort_t* aggbf    =(ushort_t*)take((size_t)N*HD*2);
  uchar_t*  x8       =(uchar_t*) take((size_t)N*HD);
  uchar_t*  h8A      =(uchar_t*) take((size_t)N*HD);
  uchar_t*  h8B      =(uchar_t*) take((size_t)N*HD);
  float*    pacc     =(float*)   take((size_t)N*4);

  const int RB=(E+EPB-1)/EPB;           // 391 (hist/reorder)
  const int CB=(N*HD/4+255)/256;        // convert blocks
  const int BB=(N+BNODES-1)/BNODES;     // 98 buckets

  hipMemsetAsync(bcnt, 0, (size_t)NBUCK*4, stream);
  k_convert_x  <<<CB, 256, 0, stream>>>(x, xbf, x8, N*HD);
  k_hist       <<<RB, 512, 0, stream>>>(ei+E, bcnt, E);
  k_scan128    <<<1, NBUCK, 0, stream>>>(bcnt, gcur, gbase);
  k_reorder    <<<RB, 512, 0, stream>>>(ei, ei+E, gcur, pairs, E);
  k_bucket_csr <<<BB, 512, 0, stream>>>(pairs, gbase, rowptr, invdeg, csr, N, E);

  dim3 gg((N+7)/8);
  dim3 gd((N+TILE-1)/TILE);

  k_gather<<<gg, 512, 0, stream>>>(x8,  aggbf, rowptr, csr, invdeg, N);
  k_dense <<<gd, 256, 0, stream>>>(xbf,  aggbf, hbfA, h8A, W1l,b1,W1r, Wlin+0,   blin, pacc, (float*)nullptr, 1, N);
  k_gather<<<gg, 512, 0, stream>>>(h8A, aggbf, rowptr, csr, invdeg, N);
  k_dense <<<gd, 256, 0, stream>>>(hbfA, aggbf, hbfB, h8B, W2l,b2,W2r, Wlin+64,  blin, pacc, (float*)nullptr, 0, N);
  k_gather<<<gg, 512, 0, stream>>>(h8B, aggbf, rowptr, csr, invdeg, N);
  k_dense <<<gd, 256, 0, stream>>>(hbfB, aggbf, hbfA, h8A, W3l,b3,W3r, Wlin+128, blin, pacc, out, 0, N);
}

// Round 15
// 217.729 us; speedup vs baseline: 5.9082x; 1.0001x over previous
//
#include <hip/hip_runtime.h>
#include <math.h>

#define N_NODES 100000
#define N_EDGES 1600000
#define HD 64
#define TILE 128
#define NBUCK 128          // dst>>10 -> 98 used buckets
#define BNODES 1024
#define EPB 4096           // edges per block in hist/reorder

typedef unsigned short ushort_t;
typedef unsigned char uchar_t;
typedef __attribute__((ext_vector_type(8))) unsigned short ushort8_t;
typedef __attribute__((ext_vector_type(8))) short short8_t;
typedef __attribute__((ext_vector_type(4))) float float4_t;
typedef __attribute__((ext_vector_type(2))) float float2_t;

__device__ __forceinline__ float bf2f(ushort_t h){
  union{unsigned u; float f;} v; v.u = ((unsigned)h)<<16; return v.f;
}
__device__ __forceinline__ ushort_t f2bf(float f){
  union{float f; unsigned u;} v; v.f=f;
  unsigned b = v.u + 0x7FFF + ((v.u>>16)&1);
  return (ushort_t)(b>>16);
}

__global__ void k_zero_bcnt(int* __restrict__ p){
  p[threadIdx.x] = 0;
}

// fused convert: x f32 -> bf16 copy + fp8(e4m3) copy
__global__ void k_convert_x(const float* __restrict__ in, ushort_t* __restrict__ obf,
                            uchar_t* __restrict__ o8, int n){
  int i = blockIdx.x*blockDim.x + threadIdx.x;
  int idx = i*4;
  if(idx+3<n){
    float4 v = *(const float4*)&in[idx];
    ushort2 a; a.x=f2bf(v.x); a.y=f2bf(v.y);
    ushort2 b; b.x=f2bf(v.z); b.y=f2bf(v.w);
    *(ushort2*)&obf[idx] = a;
    *(ushort2*)&obf[idx+2] = b;
    int p = __builtin_amdgcn_cvt_pk_fp8_f32(v.x, v.y, 0, false);
    p     = __builtin_amdgcn_cvt_pk_fp8_f32(v.z, v.w, p, true);
    *(unsigned int*)&o8[idx] = (unsigned int)p;
  } else {
    for(int k=idx;k<n;k++){
      obf[k]=f2bf(in[k]);
      int p = __builtin_amdgcn_cvt_pk_fp8_f32(in[k], 0.f, 0, false);
      o8[k] = (uchar_t)(p & 0xFF);
    }
  }
}

// ---- CSR build: coarse radix partition by dst>>10, then per-bucket finalize ----

__global__ __launch_bounds__(512) void k_hist(const int* __restrict__ dst, int* __restrict__ bcnt, int n){
  __shared__ int lh[NBUCK];
  int t=threadIdx.x;
  if(t<NBUCK) lh[t]=0;
  __syncthreads();
  int base = blockIdx.x*EPB;
  #pragma unroll
  for(int j=0;j<8;j++){
    int e = base + t + j*512;
    if(e<n) atomicAdd(&lh[dst[e]>>10], 1);
  }
  __syncthreads();
  if(t<NBUCK && lh[t]) atomicAdd(&bcnt[t], lh[t]);
}

__global__ void k_scan128(const int* __restrict__ bcnt, int* __restrict__ gcur, int* __restrict__ gbase){
  __shared__ int s[NBUCK];
  int t=threadIdx.x;
  int v=bcnt[t]; s[t]=v;
  __syncthreads();
  for(int off=1; off<NBUCK; off<<=1){
    int a=(t>=off)? s[t-off]:0;
    __syncthreads();
    s[t]+=a;
    __syncthreads();
  }
  int excl = s[t]-v;
  gcur[t]=excl;
  gbase[t]=excl;
  if(t==NBUCK-1) gbase[NBUCK]=s[t];
}

// packed pair: src (17b) | dstlocal<<17 (10b)
__global__ __launch_bounds__(512) void k_reorder(
    const int* __restrict__ src, const int* __restrict__ dst,
    int* __restrict__ gcur, int* __restrict__ pairs, int n){
  __shared__ int lh[NBUCK];
  __shared__ int lbase[NBUCK];
  int t=threadIdx.x;
  if(t<NBUCK) lh[t]=0;
  __syncthreads();
  int base = blockIdx.x*EPB;
  int bb[8], rr[8], pv[8];
  #pragma unroll
  for(int j=0;j<8;j++){
    int e = base + t + j*512;
    if(e<n){
      int d=dst[e];
      int b=d>>10;
      rr[j]=atomicAdd(&lh[b],1);
      bb[j]=b;
      pv[j]=src[e] | ((d & 1023)<<17);
    } else bb[j]=-1;
  }
  __syncthreads();
  if(t<NBUCK && lh[t]) lbase[t]=atomicAdd(&gcur[t], lh[t]);
  __syncthreads();
  #pragma unroll
  for(int j=0;j<8;j++){
    if(bb[j]>=0){
      int pos = lbase[bb[j]] + rr[j];
      pairs[pos] = pv[j];
    }
  }
}

// One block per bucket: LDS hist over 1024 local nodes -> scan -> rowptr/invdeg
// -> LDS-cursor scatter into the bucket's private csr window (one XCD's L2).
__global__ __launch_bounds__(512) void k_bucket_csr(
    const int* __restrict__ pairs, const int* __restrict__ gbase,
    int* __restrict__ rowptr, float* __restrict__ invdeg,
    int* __restrict__ csr, int nnodes, int nedges){
  __shared__ int cnt[BNODES];
  __shared__ int part[512];
  int t=threadIdx.x, b=blockIdx.x;
  int nb0 = b*BNODES;
  int e0 = gbase[b], e1 = gbase[b+1];
  cnt[t]=0; cnt[t+512]=0;
  __syncthreads();
  for(int e=e0+t; e<e1; e+=512) atomicAdd(&cnt[pairs[e]>>17], 1);
  __syncthreads();
  int c0 = cnt[2*t], c1 = cnt[2*t+1];
  part[t] = c0+c1;
  __syncthreads();
  for(int off=1; off<512; off<<=1){
    int a=(t>=off)? part[t-off]:0;
    __syncthreads();
    part[t]+=a;
    __syncthreads();
  }
  int base = part[t]-(c0+c1);
  int ex0 = base, ex1 = base+c0;
  int n_0 = nb0+2*t, n_1 = nb0+2*t+1;
  if(n_0<nnodes){ rowptr[n_0]=e0+ex0; invdeg[n_0]=1.0f/fmaxf((float)c0,1.0f); }
  if(n_1<nnodes){ rowptr[n_1]=e0+ex1; invdeg[n_1]=1.0f/fmaxf((float)c1,1.0f); }
  if(b==0 && t==0) rowptr[nnodes]=nedges;
  cnt[2*t]=ex0; cnt[2*t+1]=ex1;      // become cursors
  __syncthreads();
  for(int e=e0+t; e<e1; e+=512){
    int p = pairs[e];
    int pos = atomicAdd(&cnt[p>>17], 1);
    csr[e0+pos] = p & 0x1FFFF;
  }
}

// fp8 gather: one wave per node. slot = lane>>3 (8 edge slots), c = lane&7
// (8B feature chunk = 8 fp8). One VMEM instr gathers 8 rows (64B lines).
// agg[node] = mean of neighbor rows -> bf16.
__global__ __launch_bounds__(512) void k_gather(
    const uchar_t* __restrict__ hin8, ushort_t* __restrict__ agg,
    const int* __restrict__ rowptr, const int* __restrict__ csr,
    const float* __restrict__ invdeg, int nnodes)
{
  int t=threadIdx.x;
  int lane=t&63, wid=t>>6;
  int node=blockIdx.x*8+wid;
  if(node>=nnodes) return;
  int start=rowptr[node], end=rowptr[node+1];
  int slot = lane>>3;
  int c    = lane&7;
  float idg = invdeg[node];
  float acc[8]={0,0,0,0,0,0,0,0};
  for(int e=start; e<end; e+=16){
    int i1 = e + slot, i2 = e + 8 + slot;
    int c1 = i1<end ? i1 : end-1;
    int c2 = i2<end ? i2 : end-1;
    int s1 = csr[c1], s2 = csr[c2];
    uint2 u1 = *(const uint2*)&hin8[(size_t)s1*HD + c*8];
    uint2 u2 = *(const uint2*)&hin8[(size_t)s2*HD + c*8];
    float m1 = i1<end ? 1.f : 0.f;
    float m2 = i2<end ? 1.f : 0.f;
    float2_t f;
    f = __builtin_amdgcn_cvt_pk_f32_fp8((int)u1.x, false); acc[0]=fmaf(m1,f.x,acc[0]); acc[1]=fmaf(m1,f.y,acc[1]);
    f = __builtin_amdgcn_cvt_pk_f32_fp8((int)u1.x, true ); acc[2]=fmaf(m1,f.x,acc[2]); acc[3]=fmaf(m1,f.y,acc[3]);
    f = __builtin_amdgcn_cvt_pk_f32_fp8((int)u1.y, false); acc[4]=fmaf(m1,f.x,acc[4]); acc[5]=fmaf(m1,f.y,acc[5]);
    f = __builtin_amdgcn_cvt_pk_f32_fp8((int)u1.y, true ); acc[6]=fmaf(m1,f.x,acc[6]); acc[7]=fmaf(m1,f.y,acc[7]);
    f = __builtin_amdgcn_cvt_pk_f32_fp8((int)u2.x, false); acc[0]=fmaf(m2,f.x,acc[0]); acc[1]=fmaf(m2,f.y,acc[1]);
    f = __builtin_amdgcn_cvt_pk_f32_fp8((int)u2.x, true ); acc[2]=fmaf(m2,f.x,acc[2]); acc[3]=fmaf(m2,f.y,acc[3]);
    f = __builtin_amdgcn_cvt_pk_f32_fp8((int)u2.y, false); acc[4]=fmaf(m2,f.x,acc[4]); acc[5]=fmaf(m2,f.y,acc[5]);
    f = __builtin_amdgcn_cvt_pk_f32_fp8((int)u2.y, true ); acc[6]=fmaf(m2,f.x,acc[6]); acc[7]=fmaf(m2,f.y,acc[7]);
  }
  #pragma unroll
  for(int off=8; off<64; off<<=1){
    #pragma unroll
    for(int j=0;j<8;j++) acc[j] += __shfl_xor(acc[j], off, 64);
  }
  if(slot==0){
    ushort8_t o;
    #pragma unroll
    for(int j=0;j<8;j++) o[j] = f2bf(acc[j]*idg);
    *(ushort8_t*)&agg[(size_t)node*HD + c*8] = o;
  }
}

// MFMA dense: C[N,64] = relu([agg|h] @ [Wl;Wr] + b), fused JK dot (+sigmoid).
// Epilogue also emits the fp8 copy of h for the next layer's gather.
__global__ __launch_bounds__(256) void k_dense(
    const ushort_t* __restrict__ hin, const ushort_t* __restrict__ agg,
    ushort_t* __restrict__ hout, uchar_t* __restrict__ h8out,
    const float* __restrict__ Wl, const float* __restrict__ bvec, const float* __restrict__ Wr,
    const float* __restrict__ wseg, const float* __restrict__ blin,
    float* __restrict__ partial, float* __restrict__ finout,
    int first, int nnodes)
{
  __shared__ ushort_t sWt[64][136];   // W^T bf16: [col][k]; 272B stride -> 2-way (free)
  __shared__ ushort_t sOut[TILE][72]; // relu'd outputs bf16
  __shared__ float sB[64], sS[64];
  int t = threadIdx.x;
  int n0 = blockIdx.x*TILE;

  {
    int col = t & 63;
    int k0  = (t >> 6) * 32;
    #pragma unroll
    for (int j = 0; j < 32; ++j) {
      int k = k0 + j;
      float wv = (k < 64) ? Wl[k*64 + col] : Wr[(k-64)*64 + col];
      sWt[col][k] = f2bf(wv);
    }
  }
  if(t<64){ sB[t]=bvec[t]; sS[t]=wseg[t]; }
  __syncthreads();

  int lane = t & 63, wv_ = t >> 6;
  int r16 = lane & 15, g4 = lane >> 4;
  int nbase = n0 + wv_*32;

  float4_t acc[2][4];
  #pragma unroll
  for(int mt=0;mt<2;mt++)
    #pragma unroll
    for(int ct=0;ct<4;ct++)
      #pragma unroll
      for(int r=0;r<4;r++) acc[mt][ct][r]=0.f;

  #pragma unroll
  for (int ks = 0; ks < 4; ++ks) {
    const ushort_t* abuf = (ks < 2) ? agg : hin;   // k<64: agg, k>=64: h
    int koff = (ks & 1)*32 + g4*8;
    short8_t aF[2];
    #pragma unroll
    for (int mt = 0; mt < 2; ++mt) {
      int node = nbase + mt*16 + r16;
      if (node >= nnodes) node = nnodes-1;         // clamp; stores guarded
      aF[mt] = *(const short8_t*)&abuf[(size_t)node*HD + koff];
    }
    #pragma unroll
    for (int ct = 0; ct < 4; ++ct) {
      short8_t bF = *(const short8_t*)&sWt[ct*16 + r16][ks*32 + g4*8];
      acc[0][ct] = __builtin_amdgcn_mfma_f32_16x16x32_bf16(aF[0], bF, acc[0][ct], 0,0,0);
      acc[1][ct] = __builtin_amdgcn_mfma_f32_16x16x32_bf16(aF[1], bF, acc[1][ct], 0,0,0);
    }
  }

  #pragma unroll
  for (int mt = 0; mt < 2; ++mt)
    #pragma unroll
    for (int ct = 0; ct < 4; ++ct) {
      int col = ct*16 + r16;
      #pragma unroll
      for (int r = 0; r < 4; ++r) {
        int row = g4*4 + r;
        float v = fmaxf(acc[mt][ct][r] + sB[col], 0.f);
        sOut[wv_*32 + mt*16 + row][col] = f2bf(v);
      }
    }
  __syncthreads();

  // pass 2: vectorized stores (bf16 + fp8) + JK dot + partial/sigmoid
  {
    int nl = t >> 1, half = t & 1;
    int node = n0 + nl;
    float p = 0.f;
    #pragma unroll
    for (int i = 0; i < 4; ++i) {
      int c0 = half*32 + i*8;
      ushort8_t v = *(const ushort8_t*)&sOut[nl][c0];
      float fv[8];
      #pragma unroll
      for (int j = 0; j < 8; ++j){ fv[j]=bf2f(v[j]); p = fmaf(fv[j], sS[c0+j], p); }
      if (!finout && node < nnodes){
        *(ushort8_t*)&hout[(size_t)node*HD + c0] = v;
        int q0 = __builtin_amdgcn_cvt_pk_fp8_f32(fv[0], fv[1], 0, false);
        q0     = __builtin_amdgcn_cvt_pk_fp8_f32(fv[2], fv[3], q0, true);
        int q1 = __builtin_amdgcn_cvt_pk_fp8_f32(fv[4], fv[5], 0, false);
        q1     = __builtin_amdgcn_cvt_pk_fp8_f32(fv[6], fv[7], q1, true);
        uint2 st; st.x=(unsigned)q0; st.y=(unsigned)q1;
        *(uint2*)&h8out[(size_t)node*HD + c0] = st;
      }
    }
    p += __shfl_xor(p, 1, 64);
    if (half == 0 && node < nnodes) {
      float q = first ? (blin[0] + p) : (partial[node] + p);
      if (finout) finout[node] = 1.0f/(1.0f+expf(-q));
      else partial[node] = q;
    }
  }
}

extern "C" void kernel_launch(void* const* d_in, const int* in_sizes, int n_in,
                              void* d_out, int out_size, void* d_ws, size_t ws_size,
                              hipStream_t stream){
  const float* x    =(const float*)d_in[0];
  const int*   ei   =(const int*)  d_in[1];
  const float* W1l  =(const float*)d_in[2];
  const float* b1   =(const float*)d_in[3];
  const float* W1r  =(const float*)d_in[4];
  const float* W2l  =(const float*)d_in[5];
  const float* b2   =(const float*)d_in[6];
  const float* W2r  =(const float*)d_in[7];
  const float* W3l  =(const float*)d_in[8];
  const float* b3   =(const float*)d_in[9];
  const float* W3r  =(const float*)d_in[10];
  const float* Wlin =(const float*)d_in[11];
  const float* blin =(const float*)d_in[12];
  float* out=(float*)d_out;

  const int N=N_NODES, E=N_EDGES;
  char* ws=(char*)d_ws;
  size_t off=0;
  auto take=[&](size_t bytes)->char*{ char* p=ws+off; off=(off+bytes+255)&~(size_t)255; return p; };
  int*      bcnt     =(int*)     take((size_t)NBUCK*4);
  int*      gcur     =(int*)     take((size_t)NBUCK*4);
  int*      gbase    =(int*)     take((size_t)(NBUCK+1)*4);
  int*      rowptr   =(int*)     take((size_t)(N+1)*4);
  int*      csr      =(int*)     take((size_t)E*4);
  int*      pairs    =(int*)     take((size_t)E*4);
  float*    invdeg   =(float*)   take((size_t)N*4);
  ushort_t* xbf      =(ushort_t*)take((size_t)N*HD*2);
  ushort_t* hbfA     =(ushort_t*)take((size_t)N*HD*2);
  ushort_t* hbfB     =(ushort_t*)take((size_t)N*HD*2);
  ushort_t* aggbf    =(ushort_t*)take((size_t)N*HD*2);
  uchar_t*  x8       =(uchar_t*) take((size_t)N*HD);
  uchar_t*  h8A      =(uchar_t*) take((size_t)N*HD);
  uchar_t*  h8B      =(uchar_t*) take((size_t)N*HD);
  float*    pacc     =(float*)   take((size_t)N*4);

  const int RB=(E+EPB-1)/EPB;           // 391 (hist/reorder)
  const int CB=(N*HD/4+255)/256;        // convert blocks
  const int BB=(N+BNODES-1)/BNODES;     // 98 buckets

  k_zero_bcnt  <<<1, NBUCK, 0, stream>>>(bcnt);
  k_convert_x  <<<CB, 256, 0, stream>>>(x, xbf, x8, N*HD);
  k_hist       <<<RB, 512, 0, stream>>>(ei+E, bcnt, E);
  k_scan128    <<<1, NBUCK, 0, stream>>>(bcnt, gcur, gbase);
  k_reorder    <<<RB, 512, 0, stream>>>(ei, ei+E, gcur, pairs, E);
  k_bucket_csr <<<BB, 512, 0, stream>>>(pairs, gbase, rowptr, invdeg, csr, N, E);

  dim3 gg((N+7)/8);
  dim3 gd((N+TILE-1)/TILE);

  k_gather<<<gg, 512, 0, stream>>>(x8,  aggbf, rowptr, csr, invdeg, N);
  k_dense <<<gd, 256, 0, stream>>>(xbf,  aggbf, hbfA, h8A, W1l,b1,W1r, Wlin+0,   blin, pacc, (float*)nullptr, 1, N);
  k_gather<<<gg, 512, 0, stream>>>(h8A, aggbf, rowptr, csr, invdeg, N);
  k_dense <<<gd, 256, 0, stream>>>(hbfA, aggbf, hbfB, h8B, W2l,b2,W2r, Wlin+64,  blin, pacc, (float*)nullptr, 0, N);
  k_gather<<<gg, 512, 0, stream>>>(h8B, aggbf, rowptr, csr, invdeg, N);
  k_dense <<<gd, 256, 0, stream>>>(hbfB, aggbf, hbfA, h8A, W3l,b3,W3r, Wlin+128, blin, pacc, out, 0, N);
}

// Round 16
// 198.524 us; speedup vs baseline: 6.4798x; 1.0967x over previous
//
#include <hip/hip_runtime.h>
#include <math.h>

#define N_NODES 100000
#define N_EDGES 1600000
#define HD 64
#define TILE 128
#define NBUCK 128          // dst>>10 -> 98 used buckets
#define BNODES 1024
#define EPB 4096           // edges per block in hist/reorder

typedef unsigned short ushort_t;
typedef unsigned char uchar_t;
typedef __attribute__((ext_vector_type(8))) unsigned short ushort8_t;
typedef __attribute__((ext_vector_type(8))) short short8_t;
typedef __attribute__((ext_vector_type(4))) float float4_t;
typedef __attribute__((ext_vector_type(2))) float float2_t;

__device__ __forceinline__ float bf2f(ushort_t h){
  union{unsigned u; float f;} v; v.u = ((unsigned)h)<<16; return v.f;
}
__device__ __forceinline__ ushort_t f2bf(float f){
  union{float f; unsigned u;} v; v.f=f;
  unsigned b = v.u + 0x7FFF + ((v.u>>16)&1);
  return (ushort_t)(b>>16);
}
__device__ __forceinline__ void acc8(float* acc, uint2 u, float m){
  float2_t f;
  f=__builtin_amdgcn_cvt_pk_f32_fp8((int)u.x,false); acc[0]=fmaf(m,f.x,acc[0]); acc[1]=fmaf(m,f.y,acc[1]);
  f=__builtin_amdgcn_cvt_pk_f32_fp8((int)u.x,true ); acc[2]=fmaf(m,f.x,acc[2]); acc[3]=fmaf(m,f.y,acc[3]);
  f=__builtin_amdgcn_cvt_pk_f32_fp8((int)u.y,false); acc[4]=fmaf(m,f.x,acc[4]); acc[5]=fmaf(m,f.y,acc[5]);
  f=__builtin_amdgcn_cvt_pk_f32_fp8((int)u.y,true ); acc[6]=fmaf(m,f.x,acc[6]); acc[7]=fmaf(m,f.y,acc[7]);
}

// fused convert: x f32 -> bf16 copy + fp8(e4m3) copy; block 0 also zeroes bcnt
__global__ void k_convert_x(const float* __restrict__ in, ushort_t* __restrict__ obf,
                            uchar_t* __restrict__ o8, int* __restrict__ bcnt, int n){
  int i = blockIdx.x*blockDim.x + threadIdx.x;
  if(blockIdx.x==0 && threadIdx.x<NBUCK) bcnt[threadIdx.x]=0;
  int idx = i*4;
  if(idx+3<n){
    float4 v = *(const float4*)&in[idx];
    ushort2 a; a.x=f2bf(v.x); a.y=f2bf(v.y);
    ushort2 b; b.x=f2bf(v.z); b.y=f2bf(v.w);
    *(ushort2*)&obf[idx] = a;
    *(ushort2*)&obf[idx+2] = b;
    int p = __builtin_amdgcn_cvt_pk_fp8_f32(v.x, v.y, 0, false);
    p     = __builtin_amdgcn_cvt_pk_fp8_f32(v.z, v.w, p, true);
    *(unsigned int*)&o8[idx] = (unsigned int)p;
  } else {
    for(int k=idx;k<n;k++){
      obf[k]=f2bf(in[k]);
      int p = __builtin_amdgcn_cvt_pk_fp8_f32(in[k], 0.f, 0, false);
      o8[k] = (uchar_t)(p & 0xFF);
    }
  }
}

// ---- CSR build: coarse radix partition by dst>>10, then per-bucket finalize ----

__global__ __launch_bounds__(512) void k_hist(const int* __restrict__ dst, int* __restrict__ bcnt, int n){
  __shared__ int lh[NBUCK];
  int t=threadIdx.x;
  if(t<NBUCK) lh[t]=0;
  __syncthreads();
  int base = blockIdx.x*EPB;
  #pragma unroll
  for(int j=0;j<8;j++){
    int e = base + t + j*512;
    if(e<n) atomicAdd(&lh[dst[e]>>10], 1);
  }
  __syncthreads();
  if(t<NBUCK && lh[t]) atomicAdd(&bcnt[t], lh[t]);
}

__global__ void k_scan128(const int* __restrict__ bcnt, int* __restrict__ gcur, int* __restrict__ gbase){
  __shared__ int s[NBUCK];
  int t=threadIdx.x;
  int v=bcnt[t]; s[t]=v;
  __syncthreads();
  for(int off=1; off<NBUCK; off<<=1){
    int a=(t>=off)? s[t-off]:0;
    __syncthreads();
    s[t]+=a;
    __syncthreads();
  }
  int excl = s[t]-v;
  gcur[t]=excl;
  gbase[t]=excl;
  if(t==NBUCK-1) gbase[NBUCK]=s[t];
}

// packed pair: src (17b) | dstlocal<<17 (10b)
__global__ __launch_bounds__(512) void k_reorder(
    const int* __restrict__ src, const int* __restrict__ dst,
    int* __restrict__ gcur, int* __restrict__ pairs, int n){
  __shared__ int lh[NBUCK];
  __shared__ int lbase[NBUCK];
  int t=threadIdx.x;
  if(t<NBUCK) lh[t]=0;
  __syncthreads();
  int base = blockIdx.x*EPB;
  int bb[8], rr[8], pv[8];
  #pragma unroll
  for(int j=0;j<8;j++){
    int e = base + t + j*512;
    if(e<n){
      int d=dst[e];
      int b=d>>10;
      rr[j]=atomicAdd(&lh[b],1);
      bb[j]=b;
      pv[j]=src[e] | ((d & 1023)<<17);
    } else bb[j]=-1;
  }
  __syncthreads();
  if(t<NBUCK && lh[t]) lbase[t]=atomicAdd(&gcur[t], lh[t]);
  __syncthreads();
  #pragma unroll
  for(int j=0;j<8;j++){
    if(bb[j]>=0){
      int pos = lbase[bb[j]] + rr[j];
      pairs[pos] = pv[j];
    }
  }
}

// One block per bucket: LDS hist over 1024 local nodes -> scan -> rowptr/invdeg
// -> LDS-cursor scatter into the bucket's private csr window (one XCD's L2).
__global__ __launch_bounds__(512) void k_bucket_csr(
    const int* __restrict__ pairs, const int* __restrict__ gbase,
    int* __restrict__ rowptr, float* __restrict__ invdeg,
    int* __restrict__ csr, int nnodes, int nedges){
  __shared__ int cnt[BNODES];
  __shared__ int part[512];
  int t=threadIdx.x, b=blockIdx.x;
  int nb0 = b*BNODES;
  int e0 = gbase[b], e1 = gbase[b+1];
  cnt[t]=0; cnt[t+512]=0;
  __syncthreads();
  for(int e=e0+t; e<e1; e+=512) atomicAdd(&cnt[pairs[e]>>17], 1);
  __syncthreads();
  int c0 = cnt[2*t], c1 = cnt[2*t+1];
  part[t] = c0+c1;
  __syncthreads();
  for(int off=1; off<512; off<<=1){
    int a=(t>=off)? part[t-off]:0;
    __syncthreads();
    part[t]+=a;
    __syncthreads();
  }
  int base = part[t]-(c0+c1);
  int ex0 = base, ex1 = base+c0;
  int n_0 = nb0+2*t, n_1 = nb0+2*t+1;
  if(n_0<nnodes){ rowptr[n_0]=e0+ex0; invdeg[n_0]=1.0f/fmaxf((float)c0,1.0f); }
  if(n_1<nnodes){ rowptr[n_1]=e0+ex1; invdeg[n_1]=1.0f/fmaxf((float)c1,1.0f); }
  if(b==0 && t==0) rowptr[nnodes]=nedges;
  cnt[2*t]=ex0; cnt[2*t+1]=ex1;      // become cursors
  __syncthreads();
  for(int e=e0+t; e<e1; e+=512){
    int p = pairs[e];
    int pos = atomicAdd(&cnt[p>>17], 1);
    csr[e0+pos] = p & 0x1FFFF;
  }
}

// fp8 gather: TWO nodes per wave. slot = lane>>3 (8 edge slots), c = lane&7
// (8B = 8 fp8 features). Both nodes' first 16-edge batches are issued
// back-to-back (4 independent gather VMEMs in flight) before any accumulate;
// tails (deg>16) follow per node. agg[node] = mean of neighbor rows -> bf16.
__global__ __launch_bounds__(512) void k_gather(
    const uchar_t* __restrict__ hin8, ushort_t* __restrict__ agg,
    const int* __restrict__ rowptr, const int* __restrict__ csr,
    const float* __restrict__ invdeg, int nnodes)
{
  int t=threadIdx.x;
  int lane=t&63, wid=t>>6;
  int nA=(blockIdx.x*8+wid)*2;
  if(nA>=nnodes) return;
  int nB=nA+1;
  bool hasB = (nB<nnodes);
  int slot=lane>>3, c=lane&7;
  int rA0=rowptr[nA], rA1=rowptr[nA+1];
  int rB0=rA1, rB1=hasB? rowptr[nB+1] : rA1;
  float idgA=invdeg[nA];
  float idgB=hasB? invdeg[nB] : 0.f;
  float aA[8]={0,0,0,0,0,0,0,0}, aB[8]={0,0,0,0,0,0,0,0};

  {
    int i1=rA0+slot, i2=rA0+8+slot;
    int j1=rB0+slot, j2=rB0+8+slot;
    int ca=max(rA1-1,0), cb=max(rB1-1,0);
    int ci1=min(i1,ca), ci2=min(i2,ca);
    int cj1=min(j1,cb), cj2=min(j2,cb);
    int sA1=csr[ci1], sA2=csr[ci2];
    int sB1=csr[cj1], sB2=csr[cj2];
    uint2 uA1=*(const uint2*)&hin8[(size_t)sA1*HD + c*8];
    uint2 uA2=*(const uint2*)&hin8[(size_t)sA2*HD + c*8];
    uint2 uB1=*(const uint2*)&hin8[(size_t)sB1*HD + c*8];
    uint2 uB2=*(const uint2*)&hin8[(size_t)sB2*HD + c*8];
    acc8(aA,uA1,(i1<rA1)?1.f:0.f);
    acc8(aA,uA2,(i2<rA1)?1.f:0.f);
    acc8(aB,uB1,(j1<rB1)?1.f:0.f);
    acc8(aB,uB2,(j2<rB1)?1.f:0.f);
  }
  for(int e=rA0+16; e<rA1; e+=16){
    int i1=e+slot, i2=e+8+slot;
    int ci1=min(i1,rA1-1), ci2=min(i2,rA1-1);
    int s1=csr[ci1], s2=csr[ci2];
    uint2 u1=*(const uint2*)&hin8[(size_t)s1*HD + c*8];
    uint2 u2=*(const uint2*)&hin8[(size_t)s2*HD + c*8];
    acc8(aA,u1,(i1<rA1)?1.f:0.f);
    acc8(aA,u2,(i2<rA1)?1.f:0.f);
  }
  for(int e=rB0+16; e<rB1; e+=16){
    int i1=e+slot, i2=e+8+slot;
    int ci1=min(i1,rB1-1), ci2=min(i2,rB1-1);
    int s1=csr[ci1], s2=csr[ci2];
    uint2 u1=*(const uint2*)&hin8[(size_t)s1*HD + c*8];
    uint2 u2=*(const uint2*)&hin8[(size_t)s2*HD + c*8];
    acc8(aB,u1,(i1<rB1)?1.f:0.f);
    acc8(aB,u2,(i2<rB1)?1.f:0.f);
  }
  #pragma unroll
  for(int off=8; off<64; off<<=1){
    #pragma unroll
    for(int j=0;j<8;j++){
      aA[j] += __shfl_xor(aA[j], off, 64);
      aB[j] += __shfl_xor(aB[j], off, 64);
    }
  }
  if(slot==0){
    ushort8_t o;
    #pragma unroll
    for(int j=0;j<8;j++) o[j] = f2bf(aA[j]*idgA);
    *(ushort8_t*)&agg[(size_t)nA*HD + c*8] = o;
    if(hasB){
      #pragma unroll
      for(int j=0;j<8;j++) o[j] = f2bf(aB[j]*idgB);
      *(ushort8_t*)&agg[(size_t)nB*HD + c*8] = o;
    }
  }
}

// MFMA dense: C[N,64] = relu([agg|h] @ [Wl;Wr] + b), fused JK dot (+sigmoid).
// Epilogue also emits the fp8 copy of h for the next layer's gather.
__global__ __launch_bounds__(256) void k_dense(
    const ushort_t* __restrict__ hin, const ushort_t* __restrict__ agg,
    ushort_t* __restrict__ hout, uchar_t* __restrict__ h8out,
    const float* __restrict__ Wl, const float* __restrict__ bvec, const float* __restrict__ Wr,
    const float* __restrict__ wseg, const float* __restrict__ blin,
    float* __restrict__ partial, float* __restrict__ finout,
    int first, int nnodes)
{
  __shared__ ushort_t sWt[64][136];   // W^T bf16: [col][k]; 272B stride -> 2-way (free)
  __shared__ ushort_t sOut[TILE][72]; // relu'd outputs bf16
  __shared__ float sB[64], sS[64];
  int t = threadIdx.x;
  int n0 = blockIdx.x*TILE;

  {
    int col = t & 63;
    int k0  = (t >> 6) * 32;
    #pragma unroll
    for (int j = 0; j < 32; ++j) {
      int k = k0 + j;
      float wv = (k < 64) ? Wl[k*64 + col] : Wr[(k-64)*64 + col];
      sWt[col][k] = f2bf(wv);
    }
  }
  if(t<64){ sB[t]=bvec[t]; sS[t]=wseg[t]; }
  __syncthreads();

  int lane = t & 63, wv_ = t >> 6;
  int r16 = lane & 15, g4 = lane >> 4;
  int nbase = n0 + wv_*32;

  float4_t acc[2][4];
  #pragma unroll
  for(int mt=0;mt<2;mt++)
    #pragma unroll
    for(int ct=0;ct<4;ct++)
      #pragma unroll
      for(int r=0;r<4;r++) acc[mt][ct][r]=0.f;

  #pragma unroll
  for (int ks = 0; ks < 4; ++ks) {
    const ushort_t* abuf = (ks < 2) ? agg : hin;   // k<64: agg, k>=64: h
    int koff = (ks & 1)*32 + g4*8;
    short8_t aF[2];
    #pragma unroll
    for (int mt = 0; mt < 2; ++mt) {
      int node = nbase + mt*16 + r16;
      if (node >= nnodes) node = nnodes-1;         // clamp; stores guarded
      aF[mt] = *(const short8_t*)&abuf[(size_t)node*HD + koff];
    }
    #pragma unroll
    for (int ct = 0; ct < 4; ++ct) {
      short8_t bF = *(const short8_t*)&sWt[ct*16 + r16][ks*32 + g4*8];
      acc[0][ct] = __builtin_amdgcn_mfma_f32_16x16x32_bf16(aF[0], bF, acc[0][ct], 0,0,0);
      acc[1][ct] = __builtin_amdgcn_mfma_f32_16x16x32_bf16(aF[1], bF, acc[1][ct], 0,0,0);
    }
  }

  #pragma unroll
  for (int mt = 0; mt < 2; ++mt)
    #pragma unroll
    for (int ct = 0; ct < 4; ++ct) {
      int col = ct*16 + r16;
      #pragma unroll
      for (int r = 0; r < 4; ++r) {
        int row = g4*4 + r;
        float v = fmaxf(acc[mt][ct][r] + sB[col], 0.f);
        sOut[wv_*32 + mt*16 + row][col] = f2bf(v);
      }
    }
  __syncthreads();

  // pass 2: vectorized stores (bf16 + fp8) + JK dot + partial/sigmoid
  {
    int nl = t >> 1, half = t & 1;
    int node = n0 + nl;
    float p = 0.f;
    #pragma unroll
    for (int i = 0; i < 4; ++i) {
      int c0 = half*32 + i*8;
      ushort8_t v = *(const ushort8_t*)&sOut[nl][c0];
      float fv[8];
      #pragma unroll
      for (int j = 0; j < 8; ++j){ fv[j]=bf2f(v[j]); p = fmaf(fv[j], sS[c0+j], p); }
      if (!finout && node < nnodes){
        *(ushort8_t*)&hout[(size_t)node*HD + c0] = v;
        int q0 = __builtin_amdgcn_cvt_pk_fp8_f32(fv[0], fv[1], 0, false);
        q0     = __builtin_amdgcn_cvt_pk_fp8_f32(fv[2], fv[3], q0, true);
        int q1 = __builtin_amdgcn_cvt_pk_fp8_f32(fv[4], fv[5], 0, false);
        q1     = __builtin_amdgcn_cvt_pk_fp8_f32(fv[6], fv[7], q1, true);
        uint2 st; st.x=(unsigned)q0; st.y=(unsigned)q1;
        *(uint2*)&h8out[(size_t)node*HD + c0] = st;
      }
    }
    p += __shfl_xor(p, 1, 64);
    if (half == 0 && node < nnodes) {
      float q = first ? (blin[0] + p) : (partial[node] + p);
      if (finout) finout[node] = 1.0f/(1.0f+expf(-q));
      else partial[node] = q;
    }
  }
}

extern "C" void kernel_launch(void* const* d_in, const int* in_sizes, int n_in,
                              void* d_out, int out_size, void* d_ws, size_t ws_size,
                              hipStream_t stream){
  const float* x    =(const float*)d_in[0];
  const int*   ei   =(const int*)  d_in[1];
  const float* W1l  =(const float*)d_in[2];
  const float* b1   =(const float*)d_in[3];
  const float* W1r  =(const float*)d_in[4];
  const float* W2l  =(const float*)d_in[5];
  const float* b2   =(const float*)d_in[6];
  const float* W2r  =(const float*)d_in[7];
  const float* W3l  =(const float*)d_in[8];
  const float* b3   =(const float*)d_in[9];
  const float* W3r  =(const float*)d_in[10];
  const float* Wlin =(const float*)d_in[11];
  const float* blin =(const float*)d_in[12];
  float* out=(float*)d_out;

  const int N=N_NODES, E=N_EDGES;
  char* ws=(char*)d_ws;
  size_t off=0;
  auto take=[&](size_t bytes)->char*{ char* p=ws+off; off=(off+bytes+255)&~(size_t)255; return p; };
  int*      bcnt     =(int*)     take((size_t)NBUCK*4);
  int*      gcur     =(int*)     take((size_t)NBUCK*4);
  int*      gbase    =(int*)     take((size_t)(NBUCK+1)*4);
  int*      rowptr   =(int*)     take((size_t)(N+1)*4);
  int*      csr      =(int*)     take((size_t)E*4);
  int*      pairs    =(int*)     take((size_t)E*4);
  float*    invdeg   =(float*)   take((size_t)N*4);
  ushort_t* xbf      =(ushort_t*)take((size_t)N*HD*2);
  ushort_t* hbfA     =(ushort_t*)take((size_t)N*HD*2);
  ushort_t* hbfB     =(ushort_t*)take((size_t)N*HD*2);
  ushort_t* aggbf    =(ushort_t*)take((size_t)N*HD*2);
  uchar_t*  x8       =(uchar_t*) take((size_t)N*HD);
  uchar_t*  h8A      =(uchar_t*) take((size_t)N*HD);
  uchar_t*  h8B      =(uchar_t*) take((size_t)N*HD);
  float*    pacc     =(float*)   take((size_t)N*4);

  const int RB=(E+EPB-1)/EPB;           // 391 (hist/reorder)
  const int CB=(N*HD/4+255)/256;        // convert blocks
  const int BB=(N+BNODES-1)/BNODES;     // 98 buckets

  k_convert_x  <<<CB, 256, 0, stream>>>(x, xbf, x8, bcnt, N*HD);
  k_hist       <<<RB, 512, 0, stream>>>(ei+E, bcnt, E);
  k_scan128    <<<1, NBUCK, 0, stream>>>(bcnt, gcur, gbase);
  k_reorder    <<<RB, 512, 0, stream>>>(ei, ei+E, gcur, pairs, E);
  k_bucket_csr <<<BB, 512, 0, stream>>>(pairs, gbase, rowptr, invdeg, csr, N, E);

  dim3 gg((N+15)/16);                   // 6250 blocks, 2 nodes/wave
  dim3 gd((N+TILE-1)/TILE);

  k_gather<<<gg, 512, 0, stream>>>(x8,  aggbf, rowptr, csr, invdeg, N);
  k_dense <<<gd, 256, 0, stream>>>(xbf,  aggbf, hbfA, h8A, W1l,b1,W1r, Wlin+0,   blin, pacc, (float*)nullptr, 1, N);
  k_gather<<<gg, 512, 0, stream>>>(h8A, aggbf, rowptr, csr, invdeg, N);
  k_dense <<<gd, 256, 0, stream>>>(hbfA, aggbf, hbfB, h8B, W2l,b2,W2r, Wlin+64,  blin, pacc, (float*)nullptr, 0, N);
  k_gather<<<gg, 512, 0, stream>>>(h8B, aggbf, rowptr, csr, invdeg, N);
  k_dense <<<gd, 256, 0, stream>>>(hbfB, aggbf, hbfA, h8A, W3l,b3,W3r, Wlin+128, blin, pacc, out, 0, N);
}